// Round 5
// baseline (291.674 us; speedup 1.0000x reference)
//
#include <hip/hip_runtime.h>
#include <hip/hip_bf16.h>

#define NN 768
#define LL 8
#define HH 64
// alpha row padding: 772 floats (3088 B, 16B-aligned) breaks 768-stride conflicts
#define ALN 772

// One wave (64 lanes) computes out[c] = relu(b[c] + sum_h x_h * W[h*64+c]).
// x_h broadcast via shuffle: lane h holds x_h.
__device__ __forceinline__ float layer64(float x, const float* __restrict__ W,
                                         const float* __restrict__ b, int c) {
    float acc = b[c];
    #pragma unroll
    for (int hh = 0; hh < 64; ++hh) {
        float xh = __shfl(x, hh, 64);
        acc = fmaf(xh, W[hh * 64 + c], acc);
    }
    return fmaxf(acc, 0.0f);
}

// Kernel 1: per row r = i*8 + l (one wave per row): q,k,v MLPs + coord_mlp(v).
// fp32 staging in d_ws:
//   q_ws [L][N][H], kT_ws [L][H][N], v_ws [L][N][H], U_ws [L][N][16]
//   U[j,l,4k+0] = cmv[j,l,k]; U[j,l,4k+1+t] = cmv[j,l,k]*coord[j,l,k,t]
__global__ __launch_bounds__(256) void qkv_kernel(
    const float* __restrict__ h, const float* __restrict__ coord,
    const float* __restrict__ wq1, const float* __restrict__ bq1,
    const float* __restrict__ wq2, const float* __restrict__ bq2,
    const float* __restrict__ wk1, const float* __restrict__ bk1,
    const float* __restrict__ wk2, const float* __restrict__ bk2,
    const float* __restrict__ wv1, const float* __restrict__ bv1,
    const float* __restrict__ wv2, const float* __restrict__ bv2,
    const float* __restrict__ wc1, const float* __restrict__ bc1,
    const float* __restrict__ wc2,
    float* __restrict__ q_ws, float* __restrict__ kT_ws,
    float* __restrict__ v_ws, float* __restrict__ U_ws)
{
    const int c = threadIdx.x & 63;
    const int wv_ = threadIdx.x >> 6;
    const int r = blockIdx.x * 4 + wv_;      // 0..6143, r = i*8 + l
    const int i = r >> 3;
    const int l = r & 7;

    const float x = h[r * 64 + c];

    float t, val;
    // q
    t = layer64(x, wq1, bq1, c);
    val = layer64(t, wq2, bq2, c);
    q_ws[(l * NN + i) * 64 + c] = val;
    // k (transposed store for coalesced j-reads in attention)
    t = layer64(x, wk1, bk1, c);
    val = layer64(t, wk2, bk2, c);
    kT_ws[(l * 64 + c) * NN + i] = val;
    // v
    t = layer64(x, wv1, bv1, c);
    float vv = layer64(t, wv2, bv2, c);
    v_ws[(l * NN + i) * 64 + c] = vv;

    // coord_mlp: t1 = relu(v@wc1+bc1); cmv = t1@wc2 (no bias, no relu)
    float t1 = layer64(vv, wc1, bc1, c);
    float cm = 0.0f;
    const int kk = c & 3;
    #pragma unroll
    for (int hh = 0; hh < 64; ++hh) {
        float th = __shfl(t1, hh, 64);
        cm = fmaf(th, wc2[hh * 4 + kk], cm);
    }
    const int k2 = (c >> 2) & 3;
    const float cmk = __shfl(cm, k2, 64);
    if (c < 16) {
        const int s = c & 3;
        float uval = (s == 0) ? cmk : cmk * coord[r * 12 + k2 * 3 + (s - 1)];
        U_ws[(l * NN + i) * 16 + c] = uval;
    }
}

// Kernel 2: one block per (l, tile of 8 i's). 256 threads.
__global__ __launch_bounds__(256) void attn_kernel(
    const float* __restrict__ q_ws, const float* __restrict__ kT_ws,
    const float* __restrict__ v_ws, const float* __restrict__ U_ws,
    const float* __restrict__ h, const float* __restrict__ coord,
    float* __restrict__ h_out, float* __restrict__ x_out)
{
    const int l  = blockIdx.x & 7;
    const int i0 = (blockIdx.x >> 3) * 8;
    const int t  = threadIdx.x;
    const int lane = t & 63;
    const int w = t >> 6;

    __shared__ float qs[8][64];
    __shared__ float alpha[8][ALN];
    __shared__ float wred[4][8];
    __shared__ float rmax[8];
    __shared__ float rinv[8];
    __shared__ float part2[2][8][16];
    __shared__ float smS[8][16];

    for (int z = t; z < 512; z += 256) {
        int ii = z >> 6, cc = z & 63;
        qs[ii][cc] = q_ws[(l * NN + i0 + ii) * 64 + cc];
    }
    __syncthreads();

    // scores: thread t owns j = t, t+256, t+512 for all 8 i's
    float sc0[8], sc1[8], sc2[8];
    #pragma unroll
    for (int ii = 0; ii < 8; ++ii) { sc0[ii] = 0.f; sc1[ii] = 0.f; sc2[ii] = 0.f; }

    const float* kTl = kT_ws + (size_t)l * 64 * NN;
    for (int h4 = 0; h4 < 16; ++h4) {
        float k0[4], k1[4], k2[4];
        #pragma unroll
        for (int d = 0; d < 4; ++d) {
            const float* kr = kTl + (h4 * 4 + d) * NN;
            k0[d] = kr[t];
            k1[d] = kr[t + 256];
            k2[d] = kr[t + 512];
        }
        #pragma unroll
        for (int ii = 0; ii < 8; ++ii) {
            float4 qv = *(const float4*)&qs[ii][h4 * 4];
            sc0[ii] += qv.x * k0[0] + qv.y * k0[1] + qv.z * k0[2] + qv.w * k0[3];
            sc1[ii] += qv.x * k1[0] + qv.y * k1[1] + qv.z * k1[2] + qv.w * k1[3];
            sc2[ii] += qv.x * k2[0] + qv.y * k2[1] + qv.z * k2[2] + qv.w * k2[3];
        }
    }

    #pragma unroll
    for (int ii = 0; ii < 8; ++ii) {
        float m = fmaxf(fmaxf(sc0[ii], sc1[ii]), sc2[ii]);
        #pragma unroll
        for (int off = 32; off >= 1; off >>= 1)
            m = fmaxf(m, __shfl_xor(m, off, 64));
        if (lane == 0) wred[w][ii] = m;
    }
    __syncthreads();
    if (t < 8) rmax[t] = fmaxf(fmaxf(wred[0][t], wred[1][t]),
                               fmaxf(wred[2][t], wred[3][t]));
    __syncthreads();

    #pragma unroll
    for (int ii = 0; ii < 8; ++ii) {
        float m = rmax[ii];
        float e0 = __expf(sc0[ii] - m);
        float e1 = __expf(sc1[ii] - m);
        float e2 = __expf(sc2[ii] - m);
        alpha[ii][t] = e0;
        alpha[ii][t + 256] = e1;
        alpha[ii][t + 512] = e2;
        float s = e0 + e1 + e2;
        #pragma unroll
        for (int off = 32; off >= 1; off >>= 1)
            s += __shfl_xor(s, off, 64);
        if (lane == 0) wred[w][ii] = s;
    }
    __syncthreads();
    if (t < 8) rinv[t] = 1.0f / (wred[0][t] + wred[1][t] + wred[2][t] + wred[3][t]);
    __syncthreads();

    // h_agg: thread (w, lane) -> channels for i = i0+w and i0+w+4
    {
        const int c = lane;
        const float* vl = v_ws + (size_t)l * NN * 64;
        float acc0 = 0.f, acc1 = 0.f;
        const float4* ar0 = (const float4*)&alpha[w][0];
        const float4* ar1 = (const float4*)&alpha[w + 4][0];
        for (int j4 = 0; j4 < 192; ++j4) {
            float4 a0 = ar0[j4];
            float4 a1 = ar1[j4];
            float v0 = vl[(j4 * 4 + 0) * 64 + c];
            float v1 = vl[(j4 * 4 + 1) * 64 + c];
            float v2 = vl[(j4 * 4 + 2) * 64 + c];
            float v3 = vl[(j4 * 4 + 3) * 64 + c];
            acc0 += a0.x * v0 + a0.y * v1 + a0.z * v2 + a0.w * v3;
            acc1 += a1.x * v0 + a1.y * v1 + a1.z * v2 + a1.w * v3;
        }
        const int row0 = ((i0 + w) * 8 + l) * 64 + c;
        const int row1 = ((i0 + w + 4) * 8 + l) * 64 + c;
        h_out[row0] = h[row0] + rinv[w] * acc0;
        h_out[row1] = h[row1] + rinv[w + 4] * acc1;
    }

    // S[i][u] = sum_j alpha[i][j] * U[j][u]
    {
        const int u  = t & 15;
        const int i2 = (t >> 4) & 7;
        const int js = t >> 7;
        const float* Ul = U_ws + (size_t)l * NN * 16;
        float a = 0.f;
        const int jbeg = js * 384;
        #pragma unroll 4
        for (int j = jbeg; j < jbeg + 384; ++j)
            a += alpha[i2][j] * Ul[j * 16 + u];
        part2[js][i2][u] = a;
    }
    __syncthreads();
    if (t < 128) {
        int uu = t & 15, i3 = t >> 4;
        smS[i3][uu] = (part2[0][i3][uu] + part2[1][i3][uu]) * rinv[i3];
    }
    __syncthreads();
    if (t < 96) {
        int i4 = t / 12, kt = t % 12, k4 = kt / 3, s4 = kt % 3;
        int idx = ((i0 + i4) * 8 + l) * 12 + kt;
        float cd = coord[idx];
        float S1 = smS[i4][k4 * 4];
        float S2 = smS[i4][k4 * 4 + 1 + s4];
        x_out[idx] = cd + cd * S1 - S2;
    }
}

extern "C" void kernel_launch(void* const* d_in, const int* in_sizes, int n_in,
                              void* d_out, int out_size, void* d_ws, size_t ws_size,
                              hipStream_t stream) {
    const float* h     = (const float*)d_in[0];
    const float* coord = (const float*)d_in[1];

    float* h_out = (float*)d_out;
    float* x_out = h_out + NN * LL * HH;   // 393216 floats

    float* q_ws  = (float*)d_ws;           // [L][N][64]
    float* kT_ws = q_ws + NN * LL * HH;    // [L][64][N]
    float* v_ws  = kT_ws + NN * LL * HH;   // [L][N][64]
    float* U_ws  = v_ws + NN * LL * HH;    // [L][N][16]

    qkv_kernel<<<(NN * LL) / 4, 256, 0, stream>>>(
        h, coord,
        (const float*)d_in[2],  (const float*)d_in[3],
        (const float*)d_in[4],  (const float*)d_in[5],
        (const float*)d_in[6],  (const float*)d_in[7],
        (const float*)d_in[8],  (const float*)d_in[9],
        (const float*)d_in[10], (const float*)d_in[11],
        (const float*)d_in[12], (const float*)d_in[13],
        (const float*)d_in[14], (const float*)d_in[15],
        (const float*)d_in[16],
        q_ws, kT_ws, v_ws, U_ws);

    attn_kernel<<<(NN / 8) * LL, 256, 0, stream>>>(
        q_ws, kT_ws, v_ws, U_ws, h, coord, h_out, x_out);
}

// Round 6
// 179.515 us; speedup vs baseline: 1.6248x; 1.6248x over previous
//
#include <hip/hip_runtime.h>

#define NN 768
#define LL 8
#define HH 64
// alpha row padding: 772 floats breaks 768-stride conflicts
#define ALN 772
#define TILE_R 16

// One 64x64 layer step for a 16-row tile: thread (rg, c4) computes 4 output
// channels of row rg. IN[rg][k] is an LDS broadcast read; W rows are coalesced
// float4 global loads (L1-resident: 16KB/layer). 4 independent fma chains.
__device__ __forceinline__ float4 layer_f4(const float (*IN)[68], int rg, int c4,
                                           const float* __restrict__ W,
                                           const float* __restrict__ b) {
    float4 acc = *(const float4*)&b[c4];
    #pragma unroll 8
    for (int k = 0; k < 64; ++k) {
        const float xv = IN[rg][k];
        const float4 wv = *(const float4*)&W[k * 64 + c4];
        acc.x = fmaf(xv, wv.x, acc.x);
        acc.y = fmaf(xv, wv.y, acc.y);
        acc.z = fmaf(xv, wv.z, acc.z);
        acc.w = fmaf(xv, wv.w, acc.w);
    }
    acc.x = fmaxf(acc.x, 0.f);
    acc.y = fmaxf(acc.y, 0.f);
    acc.z = fmaxf(acc.z, 0.f);
    acc.w = fmaxf(acc.w, 0.f);
    return acc;
}

// Kernel 1 v2: 16 rows per 256-thread block (4 rows per wave, wave-local LDS).
// Staging (fp32, d_ws): q_ws [L][N][H], kT_ws [L][H][N], v_ws [L][N][H],
// U_ws [L][N][16] with U[.,4k+0]=cmv[k], U[.,4k+1+t]=cmv[k]*coord[k][t].
__global__ __launch_bounds__(256) void qkv_kernel(
    const float* __restrict__ h, const float* __restrict__ coord,
    const float* __restrict__ wq1, const float* __restrict__ bq1,
    const float* __restrict__ wq2, const float* __restrict__ bq2,
    const float* __restrict__ wk1, const float* __restrict__ bk1,
    const float* __restrict__ wk2, const float* __restrict__ bk2,
    const float* __restrict__ wv1, const float* __restrict__ bv1,
    const float* __restrict__ wv2, const float* __restrict__ bv2,
    const float* __restrict__ wc1, const float* __restrict__ bc1,
    const float* __restrict__ wc2,
    float* __restrict__ q_ws, float* __restrict__ kT_ws,
    float* __restrict__ v_ws, float* __restrict__ U_ws)
{
    const int t  = threadIdx.x;
    const int rg = t >> 4;            // row in tile, 0..15 (wave-local: 4/wave)
    const int u  = t & 15;
    const int c4 = u * 4;
    const int r  = blockIdx.x * TILE_R + rg;   // global row = i*8 + l
    const int i  = r >> 3;
    const int l  = r & 7;

    // stride 68: breaks rg-group bank aliasing (68%32=4), keeps 16B alignment
    __shared__ float A[TILE_R][68];
    __shared__ float B[TILE_R][68];

    // x tile
    *(float4*)&A[rg][c4] = *(const float4*)&h[r * 64 + c4];
    __syncthreads();

    // ---- q
    *(float4*)&B[rg][c4] = layer_f4(A, rg, c4, wq1, bq1);
    __syncthreads();
    {
        float4 q = layer_f4(B, rg, c4, wq2, bq2);
        *(float4*)&q_ws[(l * NN + i) * 64 + c4] = q;
    }
    __syncthreads();

    // ---- k (transposed scatter store for coalesced j-reads in attention)
    *(float4*)&B[rg][c4] = layer_f4(A, rg, c4, wk1, bk1);
    __syncthreads();
    {
        float4 kv = layer_f4(B, rg, c4, wk2, bk2);
        kT_ws[(l * 64 + c4 + 0) * NN + i] = kv.x;
        kT_ws[(l * 64 + c4 + 1) * NN + i] = kv.y;
        kT_ws[(l * 64 + c4 + 2) * NN + i] = kv.z;
        kT_ws[(l * 64 + c4 + 3) * NN + i] = kv.w;
    }
    __syncthreads();

    // ---- v
    *(float4*)&B[rg][c4] = layer_f4(A, rg, c4, wv1, bv1);
    __syncthreads();
    {
        float4 vv = layer_f4(B, rg, c4, wv2, bv2);
        *(float4*)&v_ws[(l * NN + i) * 64 + c4] = vv;
        __syncthreads();               // all A reads done (v1 was the last)
        *(float4*)&A[rg][c4] = vv;     // A now holds v
    }
    __syncthreads();

    // ---- coord_mlp: t1 = relu(v@wc1+bc1) -> B ; cmv = t1@wc2 (no bias/relu)
    *(float4*)&B[rg][c4] = layer_f4(A, rg, c4, wc1, bc1);
    __syncthreads();
    {
        const int kk  = u >> 2;        // 0..3  output coord channel
        const int seg = u & 3;         // 0..3  16-wide k segment
        float p = 0.f;
        #pragma unroll
        for (int k2 = 0; k2 < 16; ++k2) {
            const int k = seg * 16 + k2;
            p = fmaf(B[rg][k], wc2[k * 4 + kk], p);
        }
        // butterfly over the 4 seg lanes (lane id low 2 bits): all lanes get sum
        p += __shfl_xor(p, 1, 64);
        p += __shfl_xor(p, 2, 64);
        // this lane's U slot is u = 4*kk + seg
        float uval = (seg == 0) ? p : p * coord[r * 12 + kk * 3 + (seg - 1)];
        U_ws[(l * NN + i) * 16 + u] = uval;
    }
}

// Kernel 2: one block per (l, tile of 8 i's). 256 threads. (unchanged, verified)
__global__ __launch_bounds__(256) void attn_kernel(
    const float* __restrict__ q_ws, const float* __restrict__ kT_ws,
    const float* __restrict__ v_ws, const float* __restrict__ U_ws,
    const float* __restrict__ h, const float* __restrict__ coord,
    float* __restrict__ h_out, float* __restrict__ x_out)
{
    const int l  = blockIdx.x & 7;
    const int i0 = (blockIdx.x >> 3) * 8;
    const int t  = threadIdx.x;
    const int lane = t & 63;
    const int w = t >> 6;

    __shared__ float qs[8][64];
    __shared__ float alpha[8][ALN];
    __shared__ float wred[4][8];
    __shared__ float rmax[8];
    __shared__ float rinv[8];
    __shared__ float part2[2][8][16];
    __shared__ float smS[8][16];

    for (int z = t; z < 512; z += 256) {
        int ii = z >> 6, cc = z & 63;
        qs[ii][cc] = q_ws[(l * NN + i0 + ii) * 64 + cc];
    }
    __syncthreads();

    float sc0[8], sc1[8], sc2[8];
    #pragma unroll
    for (int ii = 0; ii < 8; ++ii) { sc0[ii] = 0.f; sc1[ii] = 0.f; sc2[ii] = 0.f; }

    const float* kTl = kT_ws + (size_t)l * 64 * NN;
    for (int h4 = 0; h4 < 16; ++h4) {
        float k0[4], k1[4], k2[4];
        #pragma unroll
        for (int d = 0; d < 4; ++d) {
            const float* kr = kTl + (h4 * 4 + d) * NN;
            k0[d] = kr[t];
            k1[d] = kr[t + 256];
            k2[d] = kr[t + 512];
        }
        #pragma unroll
        for (int ii = 0; ii < 8; ++ii) {
            float4 qv = *(const float4*)&qs[ii][h4 * 4];
            sc0[ii] += qv.x * k0[0] + qv.y * k0[1] + qv.z * k0[2] + qv.w * k0[3];
            sc1[ii] += qv.x * k1[0] + qv.y * k1[1] + qv.z * k1[2] + qv.w * k1[3];
            sc2[ii] += qv.x * k2[0] + qv.y * k2[1] + qv.z * k2[2] + qv.w * k2[3];
        }
    }

    #pragma unroll
    for (int ii = 0; ii < 8; ++ii) {
        float m = fmaxf(fmaxf(sc0[ii], sc1[ii]), sc2[ii]);
        #pragma unroll
        for (int off = 32; off >= 1; off >>= 1)
            m = fmaxf(m, __shfl_xor(m, off, 64));
        if (lane == 0) wred[w][ii] = m;
    }
    __syncthreads();
    if (t < 8) rmax[t] = fmaxf(fmaxf(wred[0][t], wred[1][t]),
                               fmaxf(wred[2][t], wred[3][t]));
    __syncthreads();

    #pragma unroll
    for (int ii = 0; ii < 8; ++ii) {
        float m = rmax[ii];
        float e0 = __expf(sc0[ii] - m);
        float e1 = __expf(sc1[ii] - m);
        float e2 = __expf(sc2[ii] - m);
        alpha[ii][t] = e0;
        alpha[ii][t + 256] = e1;
        alpha[ii][t + 512] = e2;
        float s = e0 + e1 + e2;
        #pragma unroll
        for (int off = 32; off >= 1; off >>= 1)
            s += __shfl_xor(s, off, 64);
        if (lane == 0) wred[w][ii] = s;
    }
    __syncthreads();
    if (t < 8) rinv[t] = 1.0f / (wred[0][t] + wred[1][t] + wred[2][t] + wred[3][t]);
    __syncthreads();

    // h_agg
    {
        const int c = lane;
        const float* vl = v_ws + (size_t)l * NN * 64;
        float acc0 = 0.f, acc1 = 0.f;
        const float4* ar0 = (const float4*)&alpha[w][0];
        const float4* ar1 = (const float4*)&alpha[w + 4][0];
        for (int j4 = 0; j4 < 192; ++j4) {
            float4 a0 = ar0[j4];
            float4 a1 = ar1[j4];
            float v0 = vl[(j4 * 4 + 0) * 64 + c];
            float v1 = vl[(j4 * 4 + 1) * 64 + c];
            float v2 = vl[(j4 * 4 + 2) * 64 + c];
            float v3 = vl[(j4 * 4 + 3) * 64 + c];
            acc0 += a0.x * v0 + a0.y * v1 + a0.z * v2 + a0.w * v3;
            acc1 += a1.x * v0 + a1.y * v1 + a1.z * v2 + a1.w * v3;
        }
        const int row0 = ((i0 + w) * 8 + l) * 64 + c;
        const int row1 = ((i0 + w + 4) * 8 + l) * 64 + c;
        h_out[row0] = h[row0] + rinv[w] * acc0;
        h_out[row1] = h[row1] + rinv[w + 4] * acc1;
    }

    // S[i][u] = sum_j alpha[i][j] * U[j][u]
    {
        const int u  = t & 15;
        const int i2 = (t >> 4) & 7;
        const int js = t >> 7;
        const float* Ul = U_ws + (size_t)l * NN * 16;
        float a = 0.f;
        const int jbeg = js * 384;
        #pragma unroll 4
        for (int j = jbeg; j < jbeg + 384; ++j)
            a += alpha[i2][j] * Ul[j * 16 + u];
        part2[js][i2][u] = a;
    }
    __syncthreads();
    if (t < 128) {
        int uu = t & 15, i3 = t >> 4;
        smS[i3][uu] = (part2[0][i3][uu] + part2[1][i3][uu]) * rinv[i3];
    }
    __syncthreads();
    if (t < 96) {
        int i4 = t / 12, kt = t % 12, k4 = kt / 3, s4 = kt % 3;
        int idx = ((i0 + i4) * 8 + l) * 12 + kt;
        float cd = coord[idx];
        float S1 = smS[i4][k4 * 4];
        float S2 = smS[i4][k4 * 4 + 1 + s4];
        x_out[idx] = cd + cd * S1 - S2;
    }
}

extern "C" void kernel_launch(void* const* d_in, const int* in_sizes, int n_in,
                              void* d_out, int out_size, void* d_ws, size_t ws_size,
                              hipStream_t stream) {
    const float* h     = (const float*)d_in[0];
    const float* coord = (const float*)d_in[1];

    float* h_out = (float*)d_out;
    float* x_out = h_out + NN * LL * HH;   // 393216 floats

    float* q_ws  = (float*)d_ws;           // [L][N][64]
    float* kT_ws = q_ws + NN * LL * HH;    // [L][64][N]
    float* v_ws  = kT_ws + NN * LL * HH;   // [L][N][64]
    float* U_ws  = v_ws + NN * LL * HH;    // [L][N][16]

    qkv_kernel<<<(NN * LL) / TILE_R, 256, 0, stream>>>(
        h, coord,
        (const float*)d_in[2],  (const float*)d_in[3],
        (const float*)d_in[4],  (const float*)d_in[5],
        (const float*)d_in[6],  (const float*)d_in[7],
        (const float*)d_in[8],  (const float*)d_in[9],
        (const float*)d_in[10], (const float*)d_in[11],
        (const float*)d_in[12], (const float*)d_in[13],
        (const float*)d_in[14], (const float*)d_in[15],
        (const float*)d_in[16],
        q_ws, kT_ws, v_ws, U_ws);

    attn_kernel<<<(NN / 8) * LL, 256, 0, stream>>>(
        q_ws, kT_ws, v_ws, U_ws, h, coord, h_out, x_out);
}

// Round 7
// 154.873 us; speedup vs baseline: 1.8833x; 1.1591x over previous
//
#include <hip/hip_runtime.h>

#define NN 768
#define LL 8
#define HH 64
#define ALN 772   // alpha row padding breaks 768-stride bank conflicts
#define QR 8      // qkv rows per block

// Half-K layer step: thread (rg, half, u) accumulates 32 of the 64 k-terms for
// 4 output channels of row rg, then combines halves via shfl_xor(16),
// adds bias, relu. Lanes: bit4 = half, bits0-3 = u, bit5 = rg parity.
__device__ __forceinline__ float4 layer_half(const float (*IN)[68], int rg, int c4,
                                             int k0, const float* __restrict__ W,
                                             const float* __restrict__ b) {
    float4 acc = {0.f, 0.f, 0.f, 0.f};
    #pragma unroll 8
    for (int kk = 0; kk < 32; ++kk) {
        const int k = k0 + kk;
        const float xv = IN[rg][k];
        const float4 wv = *(const float4*)&W[k * 64 + c4];
        acc.x = fmaf(xv, wv.x, acc.x);
        acc.y = fmaf(xv, wv.y, acc.y);
        acc.z = fmaf(xv, wv.z, acc.z);
        acc.w = fmaf(xv, wv.w, acc.w);
    }
    acc.x += __shfl_xor(acc.x, 16, 64);
    acc.y += __shfl_xor(acc.y, 16, 64);
    acc.z += __shfl_xor(acc.z, 16, 64);
    acc.w += __shfl_xor(acc.w, 16, 64);
    const float4 bb = *(const float4*)&b[c4];
    acc.x = fmaxf(acc.x + bb.x, 0.f);
    acc.y = fmaxf(acc.y + bb.y, 0.f);
    acc.z = fmaxf(acc.z + bb.z, 0.f);
    acc.w = fmaxf(acc.w + bb.w, 0.f);
    return acc;
}

// Kernel 1 v3: 8 rows / 256-thread block, 2-way k-split -> 768 blocks, 12 waves/CU.
__global__ __launch_bounds__(256) void qkv_kernel(
    const float* __restrict__ h, const float* __restrict__ coord,
    const float* __restrict__ wq1, const float* __restrict__ bq1,
    const float* __restrict__ wq2, const float* __restrict__ bq2,
    const float* __restrict__ wk1, const float* __restrict__ bk1,
    const float* __restrict__ wk2, const float* __restrict__ bk2,
    const float* __restrict__ wv1, const float* __restrict__ bv1,
    const float* __restrict__ wv2, const float* __restrict__ bv2,
    const float* __restrict__ wc1, const float* __restrict__ bc1,
    const float* __restrict__ wc2,
    float* __restrict__ q_ws, float* __restrict__ kT_ws,
    float* __restrict__ v_ws, float* __restrict__ U_ws)
{
    const int t    = threadIdx.x;
    const int rg   = t >> 5;          // 0..7
    const int half = (t >> 4) & 1;    // 0..1
    const int u    = t & 15;          // 0..15
    const int c4   = u * 4;
    const int k0   = half * 32;
    const int r    = blockIdx.x * QR + rg;   // global row = i*8 + l
    const int i    = r >> 3;
    const int l    = r & 7;

    __shared__ float A[QR][68];
    __shared__ float B[QR][68];

    if (t < 128) {
        const int rr = t >> 4, cc = (t & 15) * 4;
        *(float4*)&A[rr][cc] =
            *(const float4*)&h[(blockIdx.x * QR + rr) * 64 + cc];
    }
    __syncthreads();

    // ---- q
    {
        float4 s1 = layer_half(A, rg, c4, k0, wq1, bq1);
        if (half == 0) *(float4*)&B[rg][c4] = s1;
    }
    __syncthreads();
    {
        float4 q = layer_half(B, rg, c4, k0, wq2, bq2);
        if (half == 0) *(float4*)&q_ws[(l * NN + i) * 64 + c4] = q;
    }
    __syncthreads();

    // ---- k (transposed store)
    {
        float4 s1 = layer_half(A, rg, c4, k0, wk1, bk1);
        if (half == 0) *(float4*)&B[rg][c4] = s1;
    }
    __syncthreads();
    {
        float4 kv = layer_half(B, rg, c4, k0, wk2, bk2);
        if (half == 0) {
            kT_ws[(l * 64 + c4 + 0) * NN + i] = kv.x;
            kT_ws[(l * 64 + c4 + 1) * NN + i] = kv.y;
            kT_ws[(l * 64 + c4 + 2) * NN + i] = kv.z;
            kT_ws[(l * 64 + c4 + 3) * NN + i] = kv.w;
        }
    }
    __syncthreads();

    // ---- v
    {
        float4 s1 = layer_half(A, rg, c4, k0, wv1, bv1);
        if (half == 0) *(float4*)&B[rg][c4] = s1;
    }
    __syncthreads();   // also: all A-as-x reads complete after this point
    {
        float4 vv = layer_half(B, rg, c4, k0, wv2, bv2);
        if (half == 0) {
            *(float4*)&v_ws[(l * NN + i) * 64 + c4] = vv;
            *(float4*)&A[rg][c4] = vv;    // A now holds v
        }
    }
    __syncthreads();

    // ---- coord_mlp: t1 = relu(v@wc1+bc1) -> B; cmv = t1@wc2
    {
        float4 s1 = layer_half(A, rg, c4, k0, wc1, bc1);
        if (half == 0) *(float4*)&B[rg][c4] = s1;
    }
    __syncthreads();
    {
        const int s5  = t & 31;       // half*16+u
        const int kk  = s5 >> 3;      // 0..3 coord channel
        const int seg = s5 & 7;       // 0..7, 8-wide k segment
        float p = 0.f;
        #pragma unroll
        for (int k2 = 0; k2 < 8; ++k2) {
            const int k = seg * 8 + k2;
            p = fmaf(B[rg][k], wc2[k * 4 + kk], p);
        }
        p += __shfl_xor(p, 1, 64);
        p += __shfl_xor(p, 2, 64);
        p += __shfl_xor(p, 4, 64);    // all 8 seg-lanes hold cmv[rg][kk]
        if (seg < 4) {
            const int s = seg;        // U slot = 4*kk + s
            float uval = (s == 0) ? p : p * coord[r * 12 + kk * 3 + (s - 1)];
            U_ws[(l * NN + i) * 16 + kk * 4 + s] = uval;
        }
    }
}

// Kernel 2 v2: one block per (l, 8-i tile). j-split h_agg (v read once/block).
__global__ __launch_bounds__(256) void attn_kernel(
    const float* __restrict__ q_ws, const float* __restrict__ kT_ws,
    const float* __restrict__ v_ws, const float* __restrict__ U_ws,
    const float* __restrict__ h, const float* __restrict__ coord,
    float* __restrict__ h_out, float* __restrict__ x_out)
{
    const int l  = blockIdx.x & 7;
    const int i0 = (blockIdx.x >> 3) * 8;
    const int t  = threadIdx.x;
    const int lane = t & 63;
    const int w = t >> 6;

    __shared__ float qs[8][64];
    __shared__ float alpha[8][ALN];
    __shared__ float wred[4][8];
    __shared__ float rmax[8];
    __shared__ float rinv[8];
    __shared__ float partH[4][8][66];
    __shared__ float part2[2][8][16];
    __shared__ float smS[8][16];

    for (int z = t; z < 512; z += 256) {
        int ii = z >> 6, cc = z & 63;
        qs[ii][cc] = q_ws[(l * NN + i0 + ii) * 64 + cc];
    }
    __syncthreads();

    // ---- scores: thread t owns j = t, t+256, t+512 for all 8 i
    float sc0[8], sc1[8], sc2[8];
    #pragma unroll
    for (int ii = 0; ii < 8; ++ii) { sc0[ii] = 0.f; sc1[ii] = 0.f; sc2[ii] = 0.f; }

    const float* kTl = kT_ws + (size_t)l * 64 * NN;
    for (int h4 = 0; h4 < 16; ++h4) {
        float k0[4], k1[4], k2[4];
        #pragma unroll
        for (int d = 0; d < 4; ++d) {
            const float* kr = kTl + (h4 * 4 + d) * NN;
            k0[d] = kr[t];
            k1[d] = kr[t + 256];
            k2[d] = kr[t + 512];
        }
        #pragma unroll
        for (int ii = 0; ii < 8; ++ii) {
            float4 qv = *(const float4*)&qs[ii][h4 * 4];
            sc0[ii] += qv.x * k0[0] + qv.y * k0[1] + qv.z * k0[2] + qv.w * k0[3];
            sc1[ii] += qv.x * k1[0] + qv.y * k1[1] + qv.z * k1[2] + qv.w * k1[3];
            sc2[ii] += qv.x * k2[0] + qv.y * k2[1] + qv.z * k2[2] + qv.w * k2[3];
        }
    }

    #pragma unroll
    for (int ii = 0; ii < 8; ++ii) {
        float m = fmaxf(fmaxf(sc0[ii], sc1[ii]), sc2[ii]);
        #pragma unroll
        for (int off = 32; off >= 1; off >>= 1)
            m = fmaxf(m, __shfl_xor(m, off, 64));
        if (lane == 0) wred[w][ii] = m;
    }
    __syncthreads();
    if (t < 8) rmax[t] = fmaxf(fmaxf(wred[0][t], wred[1][t]),
                               fmaxf(wred[2][t], wred[3][t]));
    __syncthreads();

    #pragma unroll
    for (int ii = 0; ii < 8; ++ii) {
        float m = rmax[ii];
        float e0 = __expf(sc0[ii] - m);
        float e1 = __expf(sc1[ii] - m);
        float e2 = __expf(sc2[ii] - m);
        alpha[ii][t] = e0;
        alpha[ii][t + 256] = e1;
        alpha[ii][t + 512] = e2;
        float s = e0 + e1 + e2;
        #pragma unroll
        for (int off = 32; off >= 1; off >>= 1)
            s += __shfl_xor(s, off, 64);
        if (lane == 0) wred[w][ii] = s;
    }
    __syncthreads();
    if (t < 8) rinv[t] = 1.0f / (wred[0][t] + wred[1][t] + wred[2][t] + wred[3][t]);
    __syncthreads();

    // ---- h_agg, j-split: wave w handles j in [192w, 192w+192) for ALL 8 i.
    {
        const int c = lane;
        const float* vl = v_ws + (size_t)l * NN * 64;
        float acc[8];
        #pragma unroll
        for (int ii = 0; ii < 8; ++ii) acc[ii] = 0.f;
        const int jb = 192 * w;
        for (int j = jb; j < jb + 192; j += 4) {
            const float* vj = vl + j * 64 + c;
            const float v0 = vj[0];
            const float v1 = vj[64];
            const float v2 = vj[128];
            const float v3 = vj[192];
            #pragma unroll
            for (int ii = 0; ii < 8; ++ii) {
                float4 av = *(const float4*)&alpha[ii][j];
                acc[ii] += av.x * v0 + av.y * v1 + av.z * v2 + av.w * v3;
            }
        }
        #pragma unroll
        for (int ii = 0; ii < 8; ++ii) partH[w][ii][c] = acc[ii];
    }
    __syncthreads();
    for (int z = t; z < 512; z += 256) {
        const int ii = z >> 6, cc = z & 63;
        const float s = partH[0][ii][cc] + partH[1][ii][cc] +
                        partH[2][ii][cc] + partH[3][ii][cc];
        const int row = ((i0 + ii) * 8 + l) * 64 + cc;
        h_out[row] = h[row] + rinv[ii] * s;
    }

    // ---- S[i][u] = sum_j alpha[i][j] * U[j][u], 2-way j-split
    {
        const int u  = t & 15;
        const int i2 = (t >> 4) & 7;
        const int js = t >> 7;
        const float* Ul = U_ws + (size_t)l * NN * 16;
        float a = 0.f;
        const int jbeg = js * 384;
        for (int j = jbeg; j < jbeg + 384; j += 4) {
            float4 av = *(const float4*)&alpha[i2][j];
            a += av.x * Ul[(j + 0) * 16 + u] + av.y * Ul[(j + 1) * 16 + u] +
                 av.z * Ul[(j + 2) * 16 + u] + av.w * Ul[(j + 3) * 16 + u];
        }
        part2[js][i2][u] = a;
    }
    __syncthreads();
    if (t < 128) {
        const int uu = t & 15, i3 = t >> 4;
        smS[i3][uu] = (part2[0][i3][uu] + part2[1][i3][uu]) * rinv[i3];
    }
    __syncthreads();
    if (t < 96) {
        const int i4 = t / 12, kt = t % 12, k4 = kt / 3, s4 = kt % 3;
        const int idx = ((i0 + i4) * 8 + l) * 12 + kt;
        const float cd = coord[idx];
        const float S1 = smS[i4][k4 * 4];
        const float S2 = smS[i4][k4 * 4 + 1 + s4];
        x_out[idx] = cd + cd * S1 - S2;
    }
}

extern "C" void kernel_launch(void* const* d_in, const int* in_sizes, int n_in,
                              void* d_out, int out_size, void* d_ws, size_t ws_size,
                              hipStream_t stream) {
    const float* h     = (const float*)d_in[0];
    const float* coord = (const float*)d_in[1];

    float* h_out = (float*)d_out;
    float* x_out = h_out + NN * LL * HH;   // 393216 floats

    float* q_ws  = (float*)d_ws;           // [L][N][64]
    float* kT_ws = q_ws + NN * LL * HH;    // [L][64][N]
    float* v_ws  = kT_ws + NN * LL * HH;   // [L][N][64]
    float* U_ws  = v_ws + NN * LL * HH;    // [L][N][16]

    qkv_kernel<<<(NN * LL) / QR, 256, 0, stream>>>(
        h, coord,
        (const float*)d_in[2],  (const float*)d_in[3],
        (const float*)d_in[4],  (const float*)d_in[5],
        (const float*)d_in[6],  (const float*)d_in[7],
        (const float*)d_in[8],  (const float*)d_in[9],
        (const float*)d_in[10], (const float*)d_in[11],
        (const float*)d_in[12], (const float*)d_in[13],
        (const float*)d_in[14], (const float*)d_in[15],
        (const float*)d_in[16],
        q_ws, kT_ws, v_ws, U_ws);

    attn_kernel<<<(NN / 8) * LL, 256, 0, stream>>>(
        q_ws, kT_ws, v_ws, U_ws, h, coord, h_out, x_out);
}

// Round 9
// 148.268 us; speedup vs baseline: 1.9672x; 1.0445x over previous
//
#include <hip/hip_runtime.h>

#define NN 768
#define LL 8
#define HH 64
#define ALN 772   // alpha row padding breaks 768-stride bank conflicts
#define QR 16     // qkv rows per block

// One 64x64 layer for a 16-row tile, 4-way k-split.
// Thread (rq, ks, c4): accumulates k-range [ks*16, ks*16+16) for 4 rows
// (rbase..rbase+3) x 4 cols (c4..c4+3); each W float4 feeds 16 fma.
// Partials combined across ks lanes (lane bits 4,5) via shfl_xor; all lanes
// end with the full sum; bias+relu applied; caller stores from lead lanes.
__device__ __forceinline__ void layer16(const float (*IN)[68], int rbase, int k0,
                                        int c4, const float* __restrict__ W,
                                        const float* __restrict__ b,
                                        float4 res[4]) {
    float4 acc[4] = {{0,0,0,0},{0,0,0,0},{0,0,0,0},{0,0,0,0}};
    #pragma unroll
    for (int kk = 0; kk < 16; ++kk) {
        const int k = k0 + kk;
        const float4 wv = *(const float4*)&W[k * 64 + c4];
        #pragma unroll
        for (int rr = 0; rr < 4; ++rr) {
            const float xv = IN[rbase + rr][k];
            acc[rr].x = fmaf(xv, wv.x, acc[rr].x);
            acc[rr].y = fmaf(xv, wv.y, acc[rr].y);
            acc[rr].z = fmaf(xv, wv.z, acc[rr].z);
            acc[rr].w = fmaf(xv, wv.w, acc[rr].w);
        }
    }
    const float4 bb = *(const float4*)&b[c4];
    #pragma unroll
    for (int rr = 0; rr < 4; ++rr) {
        acc[rr].x += __shfl_xor(acc[rr].x, 16, 64);
        acc[rr].x += __shfl_xor(acc[rr].x, 32, 64);
        acc[rr].y += __shfl_xor(acc[rr].y, 16, 64);
        acc[rr].y += __shfl_xor(acc[rr].y, 32, 64);
        acc[rr].z += __shfl_xor(acc[rr].z, 16, 64);
        acc[rr].z += __shfl_xor(acc[rr].z, 32, 64);
        acc[rr].w += __shfl_xor(acc[rr].w, 16, 64);
        acc[rr].w += __shfl_xor(acc[rr].w, 32, 64);
        res[rr].x = fmaxf(acc[rr].x + bb.x, 0.f);
        res[rr].y = fmaxf(acc[rr].y + bb.y, 0.f);
        res[rr].z = fmaxf(acc[rr].z + bb.z, 0.f);
        res[rr].w = fmaxf(acc[rr].w + bb.w, 0.f);
    }
}

// Kernel 1 v4: 16 rows / 256-thread block, 4 rows/thread, 4-way k-split.
__global__ __launch_bounds__(256) void qkv_kernel(
    const float* __restrict__ h, const float* __restrict__ coord,
    const float* __restrict__ wq1, const float* __restrict__ bq1,
    const float* __restrict__ wq2, const float* __restrict__ bq2,
    const float* __restrict__ wk1, const float* __restrict__ bk1,
    const float* __restrict__ wk2, const float* __restrict__ bk2,
    const float* __restrict__ wv1, const float* __restrict__ bv1,
    const float* __restrict__ wv2, const float* __restrict__ bv2,
    const float* __restrict__ wc1, const float* __restrict__ bc1,
    const float* __restrict__ wc2,
    float* __restrict__ q_ws, float* __restrict__ kT_ws,
    float* __restrict__ v_ws, float* __restrict__ U_ws)
{
    const int t     = threadIdx.x;
    const int c4    = (t & 15) * 4;
    const int ks    = (t >> 4) & 3;
    const int k0    = ks * 16;
    const int rbase = (t >> 6) * 4;       // wave id * 4
    const bool lead = (ks == 0);
    const int r0    = blockIdx.x * QR;

    __shared__ float A[QR][68];
    __shared__ float B[QR][68];

    // x tile: 16 rows x 64 cols, one float4 per thread
    *(float4*)&A[t >> 4][(t & 15) * 4] =
        *(const float4*)&h[(r0 + (t >> 4)) * 64 + (t & 15) * 4];
    __syncthreads();

    float4 res[4];

    // ---- q
    layer16(A, rbase, k0, c4, wq1, bq1, res);
    if (lead) {
        #pragma unroll
        for (int rr = 0; rr < 4; ++rr) *(float4*)&B[rbase + rr][c4] = res[rr];
    }
    __syncthreads();
    layer16(B, rbase, k0, c4, wq2, bq2, res);
    if (lead) {
        #pragma unroll
        for (int rr = 0; rr < 4; ++rr) {
            const int g = r0 + rbase + rr, i = g >> 3, l = g & 7;
            *(float4*)&q_ws[(l * NN + i) * 64 + c4] = res[rr];
        }
    }
    __syncthreads();

    // ---- k (transposed store)
    layer16(A, rbase, k0, c4, wk1, bk1, res);
    if (lead) {
        #pragma unroll
        for (int rr = 0; rr < 4; ++rr) *(float4*)&B[rbase + rr][c4] = res[rr];
    }
    __syncthreads();
    layer16(B, rbase, k0, c4, wk2, bk2, res);
    if (lead) {
        #pragma unroll
        for (int rr = 0; rr < 4; ++rr) {
            const int g = r0 + rbase + rr, i = g >> 3, l = g & 7;
            kT_ws[(l * 64 + c4 + 0) * NN + i] = res[rr].x;
            kT_ws[(l * 64 + c4 + 1) * NN + i] = res[rr].y;
            kT_ws[(l * 64 + c4 + 2) * NN + i] = res[rr].z;
            kT_ws[(l * 64 + c4 + 3) * NN + i] = res[rr].w;
        }
    }
    __syncthreads();

    // ---- v
    layer16(A, rbase, k0, c4, wv1, bv1, res);
    if (lead) {
        #pragma unroll
        for (int rr = 0; rr < 4; ++rr) *(float4*)&B[rbase + rr][c4] = res[rr];
    }
    __syncthreads();            // all A-as-x reads complete past this barrier
    layer16(B, rbase, k0, c4, wv2, bv2, res);
    if (lead) {
        #pragma unroll
        for (int rr = 0; rr < 4; ++rr) {
            const int g = r0 + rbase + rr, i = g >> 3, l = g & 7;
            *(float4*)&v_ws[(l * NN + i) * 64 + c4] = res[rr];
            *(float4*)&A[rbase + rr][c4] = res[rr];   // A now holds v
        }
    }
    __syncthreads();

    // ---- coord_mlp: t1 = relu(v@wc1+bc1) -> B; cmv = t1@wc2 (no bias/relu)
    layer16(A, rbase, k0, c4, wc1, bc1, res);
    if (lead) {
        #pragma unroll
        for (int rr = 0; rr < 4; ++rr) *(float4*)&B[rbase + rr][c4] = res[rr];
    }
    __syncthreads();
    {
        const int row = t >> 4;          // 0..15
        const int kk  = (t >> 2) & 3;    // coord channel
        const int seg = t & 3;           // 16-wide k segment; also U sub-slot
        float p = 0.f;
        #pragma unroll
        for (int k2 = 0; k2 < 16; ++k2) {
            const int k = seg * 16 + k2;
            p = fmaf(B[row][k], wc2[k * 4 + kk], p);
        }
        p += __shfl_xor(p, 1, 64);
        p += __shfl_xor(p, 2, 64);       // all 4 seg lanes hold cmv[row][kk]
        const int g = r0 + row, i = g >> 3, l = g & 7;
        const float uval =
            (seg == 0) ? p : p * coord[g * 12 + kk * 3 + (seg - 1)];
        U_ws[(l * NN + i) * 16 + kk * 4 + seg] = uval;
    }
}

// Kernel 2 v2: one block per (l, 8-i tile). (frozen, verified)
__global__ __launch_bounds__(256) void attn_kernel(
    const float* __restrict__ q_ws, const float* __restrict__ kT_ws,
    const float* __restrict__ v_ws, const float* __restrict__ U_ws,
    const float* __restrict__ h, const float* __restrict__ coord,
    float* __restrict__ h_out, float* __restrict__ x_out)
{
    const int l  = blockIdx.x & 7;
    const int i0 = (blockIdx.x >> 3) * 8;
    const int t  = threadIdx.x;
    const int lane = t & 63;
    const int w = t >> 6;

    __shared__ float qs[8][64];
    __shared__ float alpha[8][ALN];
    __shared__ float wred[4][8];
    __shared__ float rmax[8];
    __shared__ float rinv[8];
    __shared__ float partH[4][8][66];
    __shared__ float part2[2][8][16];
    __shared__ float smS[8][16];

    for (int z = t; z < 512; z += 256) {
        int ii = z >> 6, cc = z & 63;
        qs[ii][cc] = q_ws[(l * NN + i0 + ii) * 64 + cc];
    }
    __syncthreads();

    float sc0[8], sc1[8], sc2[8];
    #pragma unroll
    for (int ii = 0; ii < 8; ++ii) { sc0[ii] = 0.f; sc1[ii] = 0.f; sc2[ii] = 0.f; }

    const float* kTl = kT_ws + (size_t)l * 64 * NN;
    for (int h4 = 0; h4 < 16; ++h4) {
        float k0[4], k1[4], k2[4];
        #pragma unroll
        for (int d = 0; d < 4; ++d) {
            const float* kr = kTl + (h4 * 4 + d) * NN;
            k0[d] = kr[t];
            k1[d] = kr[t + 256];
            k2[d] = kr[t + 512];
        }
        #pragma unroll
        for (int ii = 0; ii < 8; ++ii) {
            float4 qv = *(const float4*)&qs[ii][h4 * 4];
            sc0[ii] += qv.x * k0[0] + qv.y * k0[1] + qv.z * k0[2] + qv.w * k0[3];
            sc1[ii] += qv.x * k1[0] + qv.y * k1[1] + qv.z * k1[2] + qv.w * k1[3];
            sc2[ii] += qv.x * k2[0] + qv.y * k2[1] + qv.z * k2[2] + qv.w * k2[3];
        }
    }

    #pragma unroll
    for (int ii = 0; ii < 8; ++ii) {
        float m = fmaxf(fmaxf(sc0[ii], sc1[ii]), sc2[ii]);
        #pragma unroll
        for (int off = 32; off >= 1; off >>= 1)
            m = fmaxf(m, __shfl_xor(m, off, 64));
        if (lane == 0) wred[w][ii] = m;
    }
    __syncthreads();
    if (t < 8) rmax[t] = fmaxf(fmaxf(wred[0][t], wred[1][t]),
                               fmaxf(wred[2][t], wred[3][t]));
    __syncthreads();

    #pragma unroll
    for (int ii = 0; ii < 8; ++ii) {
        float m = rmax[ii];
        float e0 = __expf(sc0[ii] - m);
        float e1 = __expf(sc1[ii] - m);
        float e2 = __expf(sc2[ii] - m);
        alpha[ii][t] = e0;
        alpha[ii][t + 256] = e1;
        alpha[ii][t + 512] = e2;
        float s = e0 + e1 + e2;
        #pragma unroll
        for (int off = 32; off >= 1; off >>= 1)
            s += __shfl_xor(s, off, 64);
        if (lane == 0) wred[w][ii] = s;
    }
    __syncthreads();
    if (t < 8) rinv[t] = 1.0f / (wred[0][t] + wred[1][t] + wred[2][t] + wred[3][t]);
    __syncthreads();

    // h_agg, j-split across waves: v read once per block
    {
        const int c = lane;
        const float* vl = v_ws + (size_t)l * NN * 64;
        float acc[8];
        #pragma unroll
        for (int ii = 0; ii < 8; ++ii) acc[ii] = 0.f;
        const int jb = 192 * w;
        for (int j = jb; j < jb + 192; j += 4) {
            const float* vj = vl + j * 64 + c;
            const float v0 = vj[0];
            const float v1 = vj[64];
            const float v2 = vj[128];
            const float v3 = vj[192];
            #pragma unroll
            for (int ii = 0; ii < 8; ++ii) {
                float4 av = *(const float4*)&alpha[ii][j];
                acc[ii] += av.x * v0 + av.y * v1 + av.z * v2 + av.w * v3;
            }
        }
        #pragma unroll
        for (int ii = 0; ii < 8; ++ii) partH[w][ii][c] = acc[ii];
    }
    __syncthreads();
    for (int z = t; z < 512; z += 256) {
        const int ii = z >> 6, cc = z & 63;
        const float s = partH[0][ii][cc] + partH[1][ii][cc] +
                        partH[2][ii][cc] + partH[3][ii][cc];
        const int row = ((i0 + ii) * 8 + l) * 64 + cc;
        h_out[row] = h[row] + rinv[ii] * s;
    }

    // S[i][u] = sum_j alpha[i][j] * U[j][u], 2-way j-split
    {
        const int u  = t & 15;
        const int i2 = (t >> 4) & 7;
        const int js = t >> 7;
        const float* Ul = U_ws + (size_t)l * NN * 16;
        float a = 0.f;
        const int jbeg = js * 384;
        for (int j = jbeg; j < jbeg + 384; j += 4) {
            float4 av = *(const float4*)&alpha[i2][j];
            a += av.x * Ul[(j + 0) * 16 + u] + av.y * Ul[(j + 1) * 16 + u] +
                 av.z * Ul[(j + 2) * 16 + u] + av.w * Ul[(j + 3) * 16 + u];
        }
        part2[js][i2][u] = a;
    }
    __syncthreads();
    if (t < 128) {
        const int uu = t & 15, i3 = t >> 4;
        smS[i3][uu] = (part2[0][i3][uu] + part2[1][i3][uu]) * rinv[i3];
    }
    __syncthreads();
    if (t < 96) {
        const int i4 = t / 12, kt = t % 12, k4 = kt / 3, s4 = kt % 3;
        const int idx = ((i0 + i4) * 8 + l) * 12 + kt;
        const float cd = coord[idx];
        const float S1 = smS[i4][k4 * 4];
        const float S2 = smS[i4][k4 * 4 + 1 + s4];
        x_out[idx] = cd + cd * S1 - S2;
    }
}

extern "C" void kernel_launch(void* const* d_in, const int* in_sizes, int n_in,
                              void* d_out, int out_size, void* d_ws, size_t ws_size,
                              hipStream_t stream) {
    const float* h     = (const float*)d_in[0];
    const float* coord = (const float*)d_in[1];

    float* h_out = (float*)d_out;
    float* x_out = h_out + NN * LL * HH;   // 393216 floats

    float* q_ws  = (float*)d_ws;           // [L][N][64]
    float* kT_ws = q_ws + NN * LL * HH;    // [L][64][N]
    float* v_ws  = kT_ws + NN * LL * HH;   // [L][N][64]
    float* U_ws  = v_ws + NN * LL * HH;    // [L][N][16]

    qkv_kernel<<<(NN * LL) / QR, 256, 0, stream>>>(
        h, coord,
        (const float*)d_in[2],  (const float*)d_in[3],
        (const float*)d_in[4],  (const float*)d_in[5],
        (const float*)d_in[6],  (const float*)d_in[7],
        (const float*)d_in[8],  (const float*)d_in[9],
        (const float*)d_in[10], (const float*)d_in[11],
        (const float*)d_in[12], (const float*)d_in[13],
        (const float*)d_in[14], (const float*)d_in[15],
        (const float*)d_in[16],
        q_ws, kT_ws, v_ws, U_ws);

    attn_kernel<<<(NN / 8) * LL, 256, 0, stream>>>(
        q_ws, kT_ws, v_ws, U_ws, h, coord, h_out, x_out);
}

// Round 10
// 135.459 us; speedup vs baseline: 2.1532x; 1.0946x over previous
//
#include <hip/hip_runtime.h>
#include <hip/hip_bf16.h>

#define NN 768
#define LL 8
#define HH 64
#define QR 16     // qkv rows per block
#define IT 16     // attn i-tile
#define SCP 772   // fp32 score row stride (words): %32==4 -> 2-way (free)
#define ABP 776   // bf16 alpha row stride (shorts): 1552 B, 16B-aligned

typedef __attribute__((ext_vector_type(8))) short bf16x8;
typedef __attribute__((ext_vector_type(4))) float f32x4;

__device__ __forceinline__ short f2bf(float x) {
    union { __hip_bfloat16 h; short s; } u;
    u.h = __float2bfloat16(x);
    return u.s;
}

__device__ __forceinline__ bf16x8 pack8(float4 lo, float4 hi) {
    bf16x8 r;
    r[0] = f2bf(lo.x); r[1] = f2bf(lo.y); r[2] = f2bf(lo.z); r[3] = f2bf(lo.w);
    r[4] = f2bf(hi.x); r[5] = f2bf(hi.y); r[6] = f2bf(hi.z); r[7] = f2bf(hi.w);
    return r;
}

// One 64x64 layer for a 16-row tile, 4-way k-split (R9-verified).
__device__ __forceinline__ void layer16(const float (*IN)[68], int rbase, int k0,
                                        int c4, const float* __restrict__ W,
                                        const float* __restrict__ b,
                                        float4 res[4]) {
    float4 acc[4] = {{0,0,0,0},{0,0,0,0},{0,0,0,0},{0,0,0,0}};
    #pragma unroll
    for (int kk = 0; kk < 16; ++kk) {
        const int k = k0 + kk;
        const float4 wv = *(const float4*)&W[k * 64 + c4];
        #pragma unroll
        for (int rr = 0; rr < 4; ++rr) {
            const float xv = IN[rbase + rr][k];
            acc[rr].x = fmaf(xv, wv.x, acc[rr].x);
            acc[rr].y = fmaf(xv, wv.y, acc[rr].y);
            acc[rr].z = fmaf(xv, wv.z, acc[rr].z);
            acc[rr].w = fmaf(xv, wv.w, acc[rr].w);
        }
    }
    const float4 bb = *(const float4*)&b[c4];
    #pragma unroll
    for (int rr = 0; rr < 4; ++rr) {
        acc[rr].x += __shfl_xor(acc[rr].x, 16, 64);
        acc[rr].x += __shfl_xor(acc[rr].x, 32, 64);
        acc[rr].y += __shfl_xor(acc[rr].y, 16, 64);
        acc[rr].y += __shfl_xor(acc[rr].y, 32, 64);
        acc[rr].z += __shfl_xor(acc[rr].z, 16, 64);
        acc[rr].z += __shfl_xor(acc[rr].z, 32, 64);
        acc[rr].w += __shfl_xor(acc[rr].w, 16, 64);
        acc[rr].w += __shfl_xor(acc[rr].w, 32, 64);
        res[rr].x = fmaxf(acc[rr].x + bb.x, 0.f);
        res[rr].y = fmaxf(acc[rr].y + bb.y, 0.f);
        res[rr].z = fmaxf(acc[rr].z + bb.z, 0.f);
        res[rr].w = fmaxf(acc[rr].w + bb.w, 0.f);
    }
}

// Kernel 1 v5: R9 structure; stores changed for MFMA attn:
//   q_ws [L][N][64] native, k_ws [L][N][64] native,
//   vT_ws [L][64][N] transposed, UT_ws [L][16][N] transposed.
__global__ __launch_bounds__(256) void qkv_kernel(
    const float* __restrict__ h, const float* __restrict__ coord,
    const float* __restrict__ wq1, const float* __restrict__ bq1,
    const float* __restrict__ wq2, const float* __restrict__ bq2,
    const float* __restrict__ wk1, const float* __restrict__ bk1,
    const float* __restrict__ wk2, const float* __restrict__ bk2,
    const float* __restrict__ wv1, const float* __restrict__ bv1,
    const float* __restrict__ wv2, const float* __restrict__ bv2,
    const float* __restrict__ wc1, const float* __restrict__ bc1,
    const float* __restrict__ wc2,
    float* __restrict__ q_ws, float* __restrict__ k_ws,
    float* __restrict__ vT_ws, float* __restrict__ UT_ws)
{
    const int t     = threadIdx.x;
    const int c4    = (t & 15) * 4;
    const int ks    = (t >> 4) & 3;
    const int k0    = ks * 16;
    const int rbase = (t >> 6) * 4;
    const bool lead = (ks == 0);
    const int r0    = blockIdx.x * QR;

    __shared__ float A[QR][68];
    __shared__ float B[QR][68];

    *(float4*)&A[t >> 4][(t & 15) * 4] =
        *(const float4*)&h[(r0 + (t >> 4)) * 64 + (t & 15) * 4];
    __syncthreads();

    float4 res[4];

    // ---- q
    layer16(A, rbase, k0, c4, wq1, bq1, res);
    if (lead) {
        #pragma unroll
        for (int rr = 0; rr < 4; ++rr) *(float4*)&B[rbase + rr][c4] = res[rr];
    }
    __syncthreads();
    layer16(B, rbase, k0, c4, wq2, bq2, res);
    if (lead) {
        #pragma unroll
        for (int rr = 0; rr < 4; ++rr) {
            const int g = r0 + rbase + rr, i = g >> 3, l = g & 7;
            *(float4*)&q_ws[(l * NN + i) * 64 + c4] = res[rr];
        }
    }
    __syncthreads();

    // ---- k (native store)
    layer16(A, rbase, k0, c4, wk1, bk1, res);
    if (lead) {
        #pragma unroll
        for (int rr = 0; rr < 4; ++rr) *(float4*)&B[rbase + rr][c4] = res[rr];
    }
    __syncthreads();
    layer16(B, rbase, k0, c4, wk2, bk2, res);
    if (lead) {
        #pragma unroll
        for (int rr = 0; rr < 4; ++rr) {
            const int g = r0 + rbase + rr, i = g >> 3, l = g & 7;
            *(float4*)&k_ws[(l * NN + i) * 64 + c4] = res[rr];
        }
    }
    __syncthreads();

    // ---- v (transposed store)
    layer16(A, rbase, k0, c4, wv1, bv1, res);
    if (lead) {
        #pragma unroll
        for (int rr = 0; rr < 4; ++rr) *(float4*)&B[rbase + rr][c4] = res[rr];
    }
    __syncthreads();
    layer16(B, rbase, k0, c4, wv2, bv2, res);
    if (lead) {
        #pragma unroll
        for (int rr = 0; rr < 4; ++rr) {
            const int g = r0 + rbase + rr, i = g >> 3, l = g & 7;
            vT_ws[((size_t)l * 64 + c4 + 0) * NN + i] = res[rr].x;
            vT_ws[((size_t)l * 64 + c4 + 1) * NN + i] = res[rr].y;
            vT_ws[((size_t)l * 64 + c4 + 2) * NN + i] = res[rr].z;
            vT_ws[((size_t)l * 64 + c4 + 3) * NN + i] = res[rr].w;
            *(float4*)&A[rbase + rr][c4] = res[rr];   // A now holds v
        }
    }
    __syncthreads();

    // ---- coord_mlp: t1 = relu(v@wc1+bc1) -> B; cmv = t1@wc2
    layer16(A, rbase, k0, c4, wc1, bc1, res);
    if (lead) {
        #pragma unroll
        for (int rr = 0; rr < 4; ++rr) *(float4*)&B[rbase + rr][c4] = res[rr];
    }
    __syncthreads();
    {
        const int row = t >> 4;
        const int kk  = (t >> 2) & 3;
        const int seg = t & 3;
        float p = 0.f;
        #pragma unroll
        for (int k2 = 0; k2 < 16; ++k2) {
            const int k = seg * 16 + k2;
            p = fmaf(B[row][k], wc2[k * 4 + kk], p);
        }
        p += __shfl_xor(p, 1, 64);
        p += __shfl_xor(p, 2, 64);
        const int g = r0 + row, i = g >> 3, l = g & 7;
        const float uval =
            (seg == 0) ? p : p * coord[g * 12 + kk * 3 + (seg - 1)];
        UT_ws[((size_t)l * 16 + kk * 4 + seg) * NN + i] = uval;
    }
}

// Kernel 2 v3 (MFMA): one block per (l, 16-i tile), 256 threads / 4 waves.
__global__ __launch_bounds__(256) void attn_kernel(
    const float* __restrict__ q_ws, const float* __restrict__ k_ws,
    const float* __restrict__ vT_ws, const float* __restrict__ UT_ws,
    const float* __restrict__ h, const float* __restrict__ coord,
    float* __restrict__ h_out, float* __restrict__ x_out)
{
    const int l    = blockIdx.x & 7;
    const int i0   = (blockIdx.x >> 3) * IT;
    const int t    = threadIdx.x;
    const int lane = t & 63;
    const int w    = t >> 6;
    const int m    = lane & 15;     // A-row / B-col / C-col index
    const int quad = lane >> 4;

    __shared__ float sc[IT][SCP];
    __shared__ alignas(16) short al[IT][ABP];
    __shared__ float rinv_s[IT];
    __shared__ float part3[4][IT][16];
    __shared__ float smS[IT][16];

    // A-frags: q rows i0+m (K halves 0-31 / 32-63)
    bf16x8 aq0, aq1;
    {
        const float* qrow = q_ws + ((size_t)l * NN + i0 + m) * 64 + quad * 8;
        aq0 = pack8(*(const float4*)qrow,        *(const float4*)(qrow + 4));
        aq1 = pack8(*(const float4*)(qrow + 32), *(const float4*)(qrow + 36));
    }

    // ---- Phase 1: scores; wave w covers j in [192w, 192w+192)
    {
        const float* kl = k_ws + (size_t)l * NN * 64;
        for (int nt = 0; nt < 12; ++nt) {
            const int jb = 192 * w + nt * 16;
            const float* krow = kl + (size_t)(jb + m) * 64 + quad * 8;
            bf16x8 b0 = pack8(*(const float4*)krow,        *(const float4*)(krow + 4));
            bf16x8 b1 = pack8(*(const float4*)(krow + 32), *(const float4*)(krow + 36));
            f32x4 d = {0.f, 0.f, 0.f, 0.f};
            d = __builtin_amdgcn_mfma_f32_16x16x32_bf16(aq0, b0, d, 0, 0, 0);
            d = __builtin_amdgcn_mfma_f32_16x16x32_bf16(aq1, b1, d, 0, 0, 0);
            #pragma unroll
            for (int rg = 0; rg < 4; ++rg)
                sc[quad * 4 + rg][jb + m] = d[rg];
        }
    }
    __syncthreads();

    // ---- softmax: thread (row = t>>4, sub = t&15); 16-lane shfl groups
    {
        const int row = t >> 4, sub = t & 15;
        float mx = -1e30f;
        for (int n = 0; n < 48; ++n) mx = fmaxf(mx, sc[row][sub + 16 * n]);
        mx = fmaxf(mx, __shfl_xor(mx, 1, 64));
        mx = fmaxf(mx, __shfl_xor(mx, 2, 64));
        mx = fmaxf(mx, __shfl_xor(mx, 4, 64));
        mx = fmaxf(mx, __shfl_xor(mx, 8, 64));
        float s = 0.f;
        for (int n = 0; n < 48; ++n) {
            const int j = sub + 16 * n;
            const float e = __expf(sc[row][j] - mx);
            s += e;
            al[row][j] = f2bf(e);
        }
        s += __shfl_xor(s, 1, 64);
        s += __shfl_xor(s, 2, 64);
        s += __shfl_xor(s, 4, 64);
        s += __shfl_xor(s, 8, 64);
        if (sub == 0) rinv_s[row] = 1.f / s;
    }
    __syncthreads();

    // ---- Phase 2: h_agg = alpha @ v; wave w owns c-tile [16w, 16w+16)
    {
        f32x4 acc = {0.f, 0.f, 0.f, 0.f};
        const float* vrow = vT_ws + ((size_t)l * 64 + 16 * w + m) * NN;
        #pragma unroll 4
        for (int kt = 0; kt < 24; ++kt) {
            const int k0 = kt * 32;
            bf16x8 a = *(const bf16x8*)&al[m][k0 + quad * 8];
            bf16x8 b = pack8(*(const float4*)(vrow + k0 + quad * 8),
                             *(const float4*)(vrow + k0 + quad * 8 + 4));
            acc = __builtin_amdgcn_mfma_f32_16x16x32_bf16(a, b, acc, 0, 0, 0);
        }
        const int c = 16 * w + m;
        #pragma unroll
        for (int rg = 0; rg < 4; ++rg) {
            const int i = quad * 4 + rg;
            const int row = ((i0 + i) * 8 + l) * 64 + c;
            h_out[row] = h[row] + rinv_s[i] * acc[rg];
        }
    }

    // ---- Phase 3: S = alpha @ U, 4-way K-split across waves
    {
        f32x4 acc = {0.f, 0.f, 0.f, 0.f};
        const float* urow = UT_ws + ((size_t)l * 16 + m) * NN + 192 * w;
        #pragma unroll
        for (int kt = 0; kt < 6; ++kt) {
            const int k0 = kt * 32;
            bf16x8 a = *(const bf16x8*)&al[m][192 * w + k0 + quad * 8];
            bf16x8 b = pack8(*(const float4*)(urow + k0 + quad * 8),
                             *(const float4*)(urow + k0 + quad * 8 + 4));
            acc = __builtin_amdgcn_mfma_f32_16x16x32_bf16(a, b, acc, 0, 0, 0);
        }
        #pragma unroll
        for (int rg = 0; rg < 4; ++rg)
            part3[w][quad * 4 + rg][m] = acc[rg];
    }
    __syncthreads();
    {
        const int i = t >> 4, u = t & 15;
        smS[i][u] = (part3[0][i][u] + part3[1][i][u] +
                     part3[2][i][u] + part3[3][i][u]) * rinv_s[i];
    }
    __syncthreads();
    if (t < 192) {
        const int i4 = t / 12, kt = t % 12, k4 = kt / 3, s4 = kt % 3;
        const int idx = ((i0 + i4) * 8 + l) * 12 + kt;
        const float cd = coord[idx];
        x_out[idx] = cd + cd * smS[i4][k4 * 4] - smS[i4][k4 * 4 + 1 + s4];
    }
}

extern "C" void kernel_launch(void* const* d_in, const int* in_sizes, int n_in,
                              void* d_out, int out_size, void* d_ws, size_t ws_size,
                              hipStream_t stream) {
    const float* h     = (const float*)d_in[0];
    const float* coord = (const float*)d_in[1];

    float* h_out = (float*)d_out;
    float* x_out = h_out + NN * LL * HH;   // 393216 floats

    float* q_ws  = (float*)d_ws;           // [L][N][64]
    float* k_ws  = q_ws + NN * LL * HH;    // [L][N][64]
    float* vT_ws = k_ws + NN * LL * HH;    // [L][64][N]
    float* UT_ws = vT_ws + NN * LL * HH;   // [L][16][N]

    qkv_kernel<<<(NN * LL) / QR, 256, 0, stream>>>(
        h, coord,
        (const float*)d_in[2],  (const float*)d_in[3],
        (const float*)d_in[4],  (const float*)d_in[5],
        (const float*)d_in[6],  (const float*)d_in[7],
        (const float*)d_in[8],  (const float*)d_in[9],
        (const float*)d_in[10], (const float*)d_in[11],
        (const float*)d_in[12], (const float*)d_in[13],
        (const float*)d_in[14], (const float*)d_in[15],
        (const float*)d_in[16],
        q_ws, k_ws, vT_ws, UT_ws);

    attn_kernel<<<(NN / IT) * LL, 256, 0, stream>>>(
        q_ws, k_ws, vT_ws, UT_ws, h, coord, h_out, x_out);
}

// Round 11
// 116.767 us; speedup vs baseline: 2.4979x; 1.1601x over previous
//
#include <hip/hip_runtime.h>
#include <hip/hip_bf16.h>

#define NN 768
#define LL 8
#define HH 64
#define IT 16     // attn i-tile
#define SCP 772   // fp32 score row stride (words)
#define ABP 776   // bf16 alpha row stride (shorts); 1552 B, 16B-aligned

typedef __attribute__((ext_vector_type(8))) short bf16x8;
typedef __attribute__((ext_vector_type(4))) float f32x4;

__device__ __forceinline__ short f2bf(float x) {
    union { __hip_bfloat16 h; short s; } u;
    u.h = __float2bfloat16(x);
    return u.s;
}

// One 64x64 layer for a wave-private 4-row tile, 4-way k-split across lane
// bits 4-5. All lanes end with the full sum (xor-reduce); bias+relu applied.
__device__ __forceinline__ void layer4(const float (*IN)[68], int k0, int c4,
                                       const float* __restrict__ W,
                                       const float* __restrict__ b,
                                       float4 res[4]) {
    float4 acc[4] = {{0,0,0,0},{0,0,0,0},{0,0,0,0},{0,0,0,0}};
    #pragma unroll
    for (int kk = 0; kk < 16; ++kk) {
        const int k = k0 + kk;
        const float4 wv = *(const float4*)&W[k * 64 + c4];
        #pragma unroll
        for (int rr = 0; rr < 4; ++rr) {
            const float xv = IN[rr][k];
            acc[rr].x = fmaf(xv, wv.x, acc[rr].x);
            acc[rr].y = fmaf(xv, wv.y, acc[rr].y);
            acc[rr].z = fmaf(xv, wv.z, acc[rr].z);
            acc[rr].w = fmaf(xv, wv.w, acc[rr].w);
        }
    }
    const float4 bb = *(const float4*)&b[c4];
    #pragma unroll
    for (int rr = 0; rr < 4; ++rr) {
        acc[rr].x += __shfl_xor(acc[rr].x, 16, 64);
        acc[rr].x += __shfl_xor(acc[rr].x, 32, 64);
        acc[rr].y += __shfl_xor(acc[rr].y, 16, 64);
        acc[rr].y += __shfl_xor(acc[rr].y, 32, 64);
        acc[rr].z += __shfl_xor(acc[rr].z, 16, 64);
        acc[rr].z += __shfl_xor(acc[rr].z, 32, 64);
        acc[rr].w += __shfl_xor(acc[rr].w, 16, 64);
        acc[rr].w += __shfl_xor(acc[rr].w, 32, 64);
        res[rr].x = fmaxf(acc[rr].x + bb.x, 0.f);
        res[rr].y = fmaxf(acc[rr].y + bb.y, 0.f);
        res[rr].z = fmaxf(acc[rr].z + bb.z, 0.f);
        res[rr].w = fmaxf(acc[rr].w + bb.w, 0.f);
    }
}

// Kernel 1 v6: wave-task decomposition. wave-task = (4-row group, chain).
// chains: 0=q(2 layers), 1=k(2), 2=v+coord_mlp(4+tail). 4608 wave-tasks,
// 1152 blocks x 256 thr. All LDS wave-private -> NO __syncthreads.
// Staging (bf16): q_ws/k_ws [L][N][64] native, vT_ws [L][64][N], UT_ws [L][16][N].
__global__ __launch_bounds__(256) void qkv_kernel(
    const float* __restrict__ h, const float* __restrict__ coord,
    const float* __restrict__ wq1, const float* __restrict__ bq1,
    const float* __restrict__ wq2, const float* __restrict__ bq2,
    const float* __restrict__ wk1, const float* __restrict__ bk1,
    const float* __restrict__ wk2, const float* __restrict__ bk2,
    const float* __restrict__ wv1, const float* __restrict__ bv1,
    const float* __restrict__ wv2, const float* __restrict__ bv2,
    const float* __restrict__ wc1, const float* __restrict__ bc1,
    const float* __restrict__ wc2,
    short* __restrict__ q_ws, short* __restrict__ k_ws,
    short* __restrict__ vT_ws, short* __restrict__ UT_ws)
{
    const int lane  = threadIdx.x & 63;
    const int w     = threadIdx.x >> 6;
    const int wid   = blockIdx.x * 4 + w;
    const int chain = wid / 1536;          // 0..2
    const int rg    = wid - chain * 1536;  // 4-row group
    const int r0    = rg * 4;

    const int c4   = (lane & 15) * 4;
    const int ks   = (lane >> 4) & 3;
    const int k0   = ks * 16;
    const bool lead = (ks == 0);

    __shared__ float As[4][4][68];
    __shared__ float Bs[4][4][68];
    float (*A)[68] = As[w];
    float (*B)[68] = Bs[w];

    {
        const int row = lane >> 4;
        *(float4*)&A[row][c4] = *(const float4*)&h[(r0 + row) * 64 + c4];
    }
    __builtin_amdgcn_wave_barrier();

    float4 res[4];

    if (chain == 0) {
        // ---- q
        layer4(A, k0, c4, wq1, bq1, res);
        if (lead) {
            #pragma unroll
            for (int rr = 0; rr < 4; ++rr) *(float4*)&B[rr][c4] = res[rr];
        }
        __builtin_amdgcn_wave_barrier();
        layer4(B, k0, c4, wq2, bq2, res);
        if (lead) {
            #pragma unroll
            for (int rr = 0; rr < 4; ++rr) {
                const int g = r0 + rr, i = g >> 3, l = g & 7;
                short4 s;
                s.x = f2bf(res[rr].x); s.y = f2bf(res[rr].y);
                s.z = f2bf(res[rr].z); s.w = f2bf(res[rr].w);
                *(short4*)&q_ws[(l * NN + i) * 64 + c4] = s;
            }
        }
    } else if (chain == 1) {
        // ---- k
        layer4(A, k0, c4, wk1, bk1, res);
        if (lead) {
            #pragma unroll
            for (int rr = 0; rr < 4; ++rr) *(float4*)&B[rr][c4] = res[rr];
        }
        __builtin_amdgcn_wave_barrier();
        layer4(B, k0, c4, wk2, bk2, res);
        if (lead) {
            #pragma unroll
            for (int rr = 0; rr < 4; ++rr) {
                const int g = r0 + rr, i = g >> 3, l = g & 7;
                short4 s;
                s.x = f2bf(res[rr].x); s.y = f2bf(res[rr].y);
                s.z = f2bf(res[rr].z); s.w = f2bf(res[rr].w);
                *(short4*)&k_ws[(l * NN + i) * 64 + c4] = s;
            }
        }
    } else {
        // ---- v, then coord_mlp
        layer4(A, k0, c4, wv1, bv1, res);
        if (lead) {
            #pragma unroll
            for (int rr = 0; rr < 4; ++rr) *(float4*)&B[rr][c4] = res[rr];
        }
        __builtin_amdgcn_wave_barrier();
        layer4(B, k0, c4, wv2, bv2, res);
        if (lead) {
            #pragma unroll
            for (int rr = 0; rr < 4; ++rr) {
                const int g = r0 + rr, i = g >> 3, l = g & 7;
                vT_ws[((size_t)l * 64 + c4 + 0) * NN + i] = f2bf(res[rr].x);
                vT_ws[((size_t)l * 64 + c4 + 1) * NN + i] = f2bf(res[rr].y);
                vT_ws[((size_t)l * 64 + c4 + 2) * NN + i] = f2bf(res[rr].z);
                vT_ws[((size_t)l * 64 + c4 + 3) * NN + i] = f2bf(res[rr].w);
                *(float4*)&A[rr][c4] = res[rr];   // A now holds v (fp32)
            }
        }
        __builtin_amdgcn_wave_barrier();
        layer4(A, k0, c4, wc1, bc1, res);
        if (lead) {
            #pragma unroll
            for (int rr = 0; rr < 4; ++rr) *(float4*)&B[rr][c4] = res[rr];
        }
        __builtin_amdgcn_wave_barrier();
        {
            const int row = lane >> 4;       // 0..3
            const int kk  = (lane >> 2) & 3; // coord channel
            const int seg = lane & 3;        // 16-wide k segment / U sub-slot
            float p = 0.f;
            #pragma unroll
            for (int k2 = 0; k2 < 16; ++k2) {
                const int k = seg * 16 + k2;
                p = fmaf(B[row][k], wc2[k * 4 + kk], p);
            }
            p += __shfl_xor(p, 1, 64);
            p += __shfl_xor(p, 2, 64);       // all 4 seg lanes hold cmv
            const int g = r0 + row, i = g >> 3, l = g & 7;
            const float uval =
                (seg == 0) ? p : p * coord[g * 12 + kk * 3 + (seg - 1)];
            UT_ws[((size_t)l * 16 + kk * 4 + seg) * NN + i] = f2bf(uval);
        }
    }
}

// Kernel 2 v4 (MFMA, bf16 staging): one block per (l, 16-i tile), 4 waves.
__global__ __launch_bounds__(256) void attn_kernel(
    const short* __restrict__ q_ws, const short* __restrict__ k_ws,
    const short* __restrict__ vT_ws, const short* __restrict__ UT_ws,
    const float* __restrict__ h, const float* __restrict__ coord,
    float* __restrict__ h_out, float* __restrict__ x_out)
{
    const int l    = blockIdx.x & 7;
    const int i0   = (blockIdx.x >> 3) * IT;
    const int t    = threadIdx.x;
    const int lane = t & 63;
    const int w    = t >> 6;
    const int m    = lane & 15;
    const int quad = lane >> 4;

    __shared__ float sc[IT][SCP];
    __shared__ alignas(16) short al[IT][ABP];
    __shared__ float rinv_s[IT];
    __shared__ float part3[4][IT][16];
    __shared__ float smS[IT][16];

    // A-frags: q rows i0+m, K halves
    const bf16x8 aq0 = *(const bf16x8*)&q_ws[((size_t)l * NN + i0 + m) * 64 + quad * 8];
    const bf16x8 aq1 = *(const bf16x8*)&q_ws[((size_t)l * NN + i0 + m) * 64 + 32 + quad * 8];

    // ---- Phase 1: scores; wave w covers j in [192w, 192w+192)
    {
        const short* kl = k_ws + (size_t)l * NN * 64;
        for (int nt = 0; nt < 12; ++nt) {
            const int jb = 192 * w + nt * 16;
            const short* krow = kl + (size_t)(jb + m) * 64;
            bf16x8 b0 = *(const bf16x8*)(krow + quad * 8);
            bf16x8 b1 = *(const bf16x8*)(krow + 32 + quad * 8);
            f32x4 d = {0.f, 0.f, 0.f, 0.f};
            d = __builtin_amdgcn_mfma_f32_16x16x32_bf16(aq0, b0, d, 0, 0, 0);
            d = __builtin_amdgcn_mfma_f32_16x16x32_bf16(aq1, b1, d, 0, 0, 0);
            #pragma unroll
            for (int rg = 0; rg < 4; ++rg)
                sc[quad * 4 + rg][jb + m] = d[rg];
        }
    }
    __syncthreads();

    // ---- softmax: thread group (row = t>>4, sub = t&15)
    {
        const int row = t >> 4, sub = t & 15;
        float mx = -1e30f;
        for (int n = 0; n < 48; ++n) mx = fmaxf(mx, sc[row][sub + 16 * n]);
        mx = fmaxf(mx, __shfl_xor(mx, 1, 64));
        mx = fmaxf(mx, __shfl_xor(mx, 2, 64));
        mx = fmaxf(mx, __shfl_xor(mx, 4, 64));
        mx = fmaxf(mx, __shfl_xor(mx, 8, 64));
        float s = 0.f;
        for (int n = 0; n < 48; ++n) {
            const int j = sub + 16 * n;
            const float e = __expf(sc[row][j] - mx);
            s += e;
            al[row][j] = f2bf(e);
        }
        s += __shfl_xor(s, 1, 64);
        s += __shfl_xor(s, 2, 64);
        s += __shfl_xor(s, 4, 64);
        s += __shfl_xor(s, 8, 64);
        if (sub == 0) rinv_s[row] = 1.f / s;
    }
    __syncthreads();

    // ---- Phase 2: h_agg = alpha @ v; wave w owns c-tile [16w, 16w+16)
    {
        f32x4 acc = {0.f, 0.f, 0.f, 0.f};
        const short* vrow = vT_ws + ((size_t)l * 64 + 16 * w + m) * NN;
        #pragma unroll 4
        for (int kt = 0; kt < 24; ++kt) {
            const int k0 = kt * 32;
            bf16x8 a = *(const bf16x8*)&al[m][k0 + quad * 8];
            bf16x8 b = *(const bf16x8*)(vrow + k0 + quad * 8);
            acc = __builtin_amdgcn_mfma_f32_16x16x32_bf16(a, b, acc, 0, 0, 0);
        }
        const int c = 16 * w + m;
        #pragma unroll
        for (int rg = 0; rg < 4; ++rg) {
            const int i = quad * 4 + rg;
            const int row = ((i0 + i) * 8 + l) * 64 + c;
            h_out[row] = h[row] + rinv_s[i] * acc[rg];
        }
    }

    // ---- Phase 3: S = alpha @ U, 4-way K-split across waves
    {
        f32x4 acc = {0.f, 0.f, 0.f, 0.f};
        const short* urow = UT_ws + ((size_t)l * 16 + m) * NN + 192 * w;
        #pragma unroll
        for (int kt = 0; kt < 6; ++kt) {
            const int k0 = kt * 32;
            bf16x8 a = *(const bf16x8*)&al[m][192 * w + k0 + quad * 8];
            bf16x8 b = *(const bf16x8*)(urow + k0 + quad * 8);
            acc = __builtin_amdgcn_mfma_f32_16x16x32_bf16(a, b, acc, 0, 0, 0);
        }
        #pragma unroll
        for (int rg = 0; rg < 4; ++rg)
            part3[w][quad * 4 + rg][m] = acc[rg];
    }
    __syncthreads();
    {
        const int i = t >> 4, u = t & 15;
        smS[i][u] = (part3[0][i][u] + part3[1][i][u] +
                     part3[2][i][u] + part3[3][i][u]) * rinv_s[i];
    }
    __syncthreads();
    if (t < 192) {
        const int i4 = t / 12, kt = t % 12, k4 = kt / 3, s4 = kt % 3;
        const int idx = ((i0 + i4) * 8 + l) * 12 + kt;
        const float cd = coord[idx];
        x_out[idx] = cd + cd * smS[i4][k4 * 4] - smS[i4][k4 * 4 + 1 + s4];
    }
}

extern "C" void kernel_launch(void* const* d_in, const int* in_sizes, int n_in,
                              void* d_out, int out_size, void* d_ws, size_t ws_size,
                              hipStream_t stream) {
    const float* h     = (const float*)d_in[0];
    const float* coord = (const float*)d_in[1];

    float* h_out = (float*)d_out;
    float* x_out = h_out + NN * LL * HH;     // 393216 floats

    short* q_ws  = (short*)d_ws;             // [L][N][64] bf16
    short* k_ws  = q_ws + NN * LL * HH;      // [L][N][64] bf16
    short* vT_ws = k_ws + NN * LL * HH;      // [L][64][N] bf16
    short* UT_ws = vT_ws + NN * LL * HH;     // [L][16][N] bf16

    qkv_kernel<<<1152, 256, 0, stream>>>(
        h, coord,
        (const float*)d_in[2],  (const float*)d_in[3],
        (const float*)d_in[4],  (const float*)d_in[5],
        (const float*)d_in[6],  (const float*)d_in[7],
        (const float*)d_in[8],  (const float*)d_in[9],
        (const float*)d_in[10], (const float*)d_in[11],
        (const float*)d_in[12], (const float*)d_in[13],
        (const float*)d_in[14], (const float*)d_in[15],
        (const float*)d_in[16],
        q_ws, k_ws, vT_ws, UT_ws);

    attn_kernel<<<(NN / IT) * LL, 256, 0, stream>>>(
        q_ws, k_ws, vT_ws, UT_ws, h, coord, h_out, x_out);
}

// Round 12
// 115.216 us; speedup vs baseline: 2.5315x; 1.0135x over previous
//
#include <hip/hip_runtime.h>
#include <hip/hip_bf16.h>

#define NN 768
#define LL 8
#define HH 64
#define IT 16     // attn i-tile
#define SCP 772   // fp32 score row stride (words)
#define ABP 776   // bf16 alpha row stride (shorts); 1552 B, 16B-aligned

typedef __attribute__((ext_vector_type(8))) short bf16x8;
typedef __attribute__((ext_vector_type(4))) float f32x4;

__device__ __forceinline__ short f2bf(float x) {
    union { __hip_bfloat16 h; short s; } u;
    u.h = __float2bfloat16(x);
    return u.s;
}

// One 64x64 layer for a wave-private 4-row tile, 4-way k-split across lane
// bits 4-5. All lanes end with the full sum (xor-reduce); bias+relu applied.
__device__ __forceinline__ void layer4(const float (*IN)[68], int k0, int c4,
                                       const float* __restrict__ W,
                                       const float* __restrict__ b,
                                       float4 res[4]) {
    float4 acc[4] = {{0,0,0,0},{0,0,0,0},{0,0,0,0},{0,0,0,0}};
    #pragma unroll
    for (int kk = 0; kk < 16; ++kk) {
        const int k = k0 + kk;
        const float4 wv = *(const float4*)&W[k * 64 + c4];
        #pragma unroll
        for (int rr = 0; rr < 4; ++rr) {
            const float xv = IN[rr][k];
            acc[rr].x = fmaf(xv, wv.x, acc[rr].x);
            acc[rr].y = fmaf(xv, wv.y, acc[rr].y);
            acc[rr].z = fmaf(xv, wv.z, acc[rr].z);
            acc[rr].w = fmaf(xv, wv.w, acc[rr].w);
        }
    }
    const float4 bb = *(const float4*)&b[c4];
    #pragma unroll
    for (int rr = 0; rr < 4; ++rr) {
        acc[rr].x += __shfl_xor(acc[rr].x, 16, 64);
        acc[rr].x += __shfl_xor(acc[rr].x, 32, 64);
        acc[rr].y += __shfl_xor(acc[rr].y, 16, 64);
        acc[rr].y += __shfl_xor(acc[rr].y, 32, 64);
        acc[rr].z += __shfl_xor(acc[rr].z, 16, 64);
        acc[rr].z += __shfl_xor(acc[rr].z, 32, 64);
        acc[rr].w += __shfl_xor(acc[rr].w, 16, 64);
        acc[rr].w += __shfl_xor(acc[rr].w, 32, 64);
        res[rr].x = fmaxf(acc[rr].x + bb.x, 0.f);
        res[rr].y = fmaxf(acc[rr].y + bb.y, 0.f);
        res[rr].z = fmaxf(acc[rr].z + bb.z, 0.f);
        res[rr].w = fmaxf(acc[rr].w + bb.w, 0.f);
    }
}

// Kernel 1 v6 (frozen from R11): wave-task decomposition, no __syncthreads.
__global__ __launch_bounds__(256) void qkv_kernel(
    const float* __restrict__ h, const float* __restrict__ coord,
    const float* __restrict__ wq1, const float* __restrict__ bq1,
    const float* __restrict__ wq2, const float* __restrict__ bq2,
    const float* __restrict__ wk1, const float* __restrict__ bk1,
    const float* __restrict__ wk2, const float* __restrict__ bk2,
    const float* __restrict__ wv1, const float* __restrict__ bv1,
    const float* __restrict__ wv2, const float* __restrict__ bv2,
    const float* __restrict__ wc1, const float* __restrict__ bc1,
    const float* __restrict__ wc2,
    short* __restrict__ q_ws, short* __restrict__ k_ws,
    short* __restrict__ vT_ws, short* __restrict__ UT_ws)
{
    const int lane  = threadIdx.x & 63;
    const int w     = threadIdx.x >> 6;
    const int wid   = blockIdx.x * 4 + w;
    const int chain = wid / 1536;          // 0..2
    const int rg    = wid - chain * 1536;  // 4-row group
    const int r0    = rg * 4;

    const int c4   = (lane & 15) * 4;
    const int ks   = (lane >> 4) & 3;
    const int k0   = ks * 16;
    const bool lead = (ks == 0);

    __shared__ float As[4][4][68];
    __shared__ float Bs[4][4][68];
    float (*A)[68] = As[w];
    float (*B)[68] = Bs[w];

    {
        const int row = lane >> 4;
        *(float4*)&A[row][c4] = *(const float4*)&h[(r0 + row) * 64 + c4];
    }
    __builtin_amdgcn_wave_barrier();

    float4 res[4];

    if (chain == 0) {
        layer4(A, k0, c4, wq1, bq1, res);
        if (lead) {
            #pragma unroll
            for (int rr = 0; rr < 4; ++rr) *(float4*)&B[rr][c4] = res[rr];
        }
        __builtin_amdgcn_wave_barrier();
        layer4(B, k0, c4, wq2, bq2, res);
        if (lead) {
            #pragma unroll
            for (int rr = 0; rr < 4; ++rr) {
                const int g = r0 + rr, i = g >> 3, l = g & 7;
                short4 s;
                s.x = f2bf(res[rr].x); s.y = f2bf(res[rr].y);
                s.z = f2bf(res[rr].z); s.w = f2bf(res[rr].w);
                *(short4*)&q_ws[(l * NN + i) * 64 + c4] = s;
            }
        }
    } else if (chain == 1) {
        layer4(A, k0, c4, wk1, bk1, res);
        if (lead) {
            #pragma unroll
            for (int rr = 0; rr < 4; ++rr) *(float4*)&B[rr][c4] = res[rr];
        }
        __builtin_amdgcn_wave_barrier();
        layer4(B, k0, c4, wk2, bk2, res);
        if (lead) {
            #pragma unroll
            for (int rr = 0; rr < 4; ++rr) {
                const int g = r0 + rr, i = g >> 3, l = g & 7;
                short4 s;
                s.x = f2bf(res[rr].x); s.y = f2bf(res[rr].y);
                s.z = f2bf(res[rr].z); s.w = f2bf(res[rr].w);
                *(short4*)&k_ws[(l * NN + i) * 64 + c4] = s;
            }
        }
    } else {
        layer4(A, k0, c4, wv1, bv1, res);
        if (lead) {
            #pragma unroll
            for (int rr = 0; rr < 4; ++rr) *(float4*)&B[rr][c4] = res[rr];
        }
        __builtin_amdgcn_wave_barrier();
        layer4(B, k0, c4, wv2, bv2, res);
        if (lead) {
            #pragma unroll
            for (int rr = 0; rr < 4; ++rr) {
                const int g = r0 + rr, i = g >> 3, l = g & 7;
                vT_ws[((size_t)l * 64 + c4 + 0) * NN + i] = f2bf(res[rr].x);
                vT_ws[((size_t)l * 64 + c4 + 1) * NN + i] = f2bf(res[rr].y);
                vT_ws[((size_t)l * 64 + c4 + 2) * NN + i] = f2bf(res[rr].z);
                vT_ws[((size_t)l * 64 + c4 + 3) * NN + i] = f2bf(res[rr].w);
                *(float4*)&A[rr][c4] = res[rr];   // A now holds v (fp32)
            }
        }
        __builtin_amdgcn_wave_barrier();
        layer4(A, k0, c4, wc1, bc1, res);
        if (lead) {
            #pragma unroll
            for (int rr = 0; rr < 4; ++rr) *(float4*)&B[rr][c4] = res[rr];
        }
        __builtin_amdgcn_wave_barrier();
        {
            const int row = lane >> 4;
            const int kk  = (lane >> 2) & 3;
            const int seg = lane & 3;
            float p = 0.f;
            #pragma unroll
            for (int k2 = 0; k2 < 16; ++k2) {
                const int k = seg * 16 + k2;
                p = fmaf(B[row][k], wc2[k * 4 + kk], p);
            }
            p += __shfl_xor(p, 1, 64);
            p += __shfl_xor(p, 2, 64);
            const int g = r0 + row, i = g >> 3, l = g & 7;
            const float uval =
                (seg == 0) ? p : p * coord[g * 12 + kk * 3 + (seg - 1)];
            UT_ws[((size_t)l * 16 + kk * 4 + seg) * NN + i] = f2bf(uval);
        }
    }
}

// Kernel 2 v5 (MFMA, bf16 staging, vectorized softmax).
__global__ __launch_bounds__(256) void attn_kernel(
    const short* __restrict__ q_ws, const short* __restrict__ k_ws,
    const short* __restrict__ vT_ws, const short* __restrict__ UT_ws,
    const float* __restrict__ h, const float* __restrict__ coord,
    float* __restrict__ h_out, float* __restrict__ x_out)
{
    const int l    = blockIdx.x & 7;
    const int i0   = (blockIdx.x >> 3) * IT;
    const int t    = threadIdx.x;
    const int lane = t & 63;
    const int w    = t >> 6;
    const int m    = lane & 15;
    const int quad = lane >> 4;

    __shared__ float sc[IT][SCP];
    __shared__ alignas(16) short al[IT][ABP];
    __shared__ float rinv_s[IT];
    __shared__ float part3[4][IT][16];
    __shared__ float smS[IT][16];

    // A-frags: q rows i0+m, K halves
    const bf16x8 aq0 = *(const bf16x8*)&q_ws[((size_t)l * NN + i0 + m) * 64 + quad * 8];
    const bf16x8 aq1 = *(const bf16x8*)&q_ws[((size_t)l * NN + i0 + m) * 64 + 32 + quad * 8];

    // ---- Phase 1: scores; wave w covers j in [192w, 192w+192)
    {
        const short* kl = k_ws + (size_t)l * NN * 64;
        for (int nt = 0; nt < 12; ++nt) {
            const int jb = 192 * w + nt * 16;
            const short* krow = kl + (size_t)(jb + m) * 64;
            bf16x8 b0 = *(const bf16x8*)(krow + quad * 8);
            bf16x8 b1 = *(const bf16x8*)(krow + 32 + quad * 8);
            f32x4 d = {0.f, 0.f, 0.f, 0.f};
            d = __builtin_amdgcn_mfma_f32_16x16x32_bf16(aq0, b0, d, 0, 0, 0);
            d = __builtin_amdgcn_mfma_f32_16x16x32_bf16(aq1, b1, d, 0, 0, 0);
            #pragma unroll
            for (int rg = 0; rg < 4; ++rg)
                sc[quad * 4 + rg][jb + m] = d[rg];
        }
    }
    __syncthreads();

    // ---- softmax (vectorized): thread (r = t>>4, sub = t&15) owns the j-comb
    // j = sub*4 + 64*jj (jj=0..11): 12 ds_read_b128, fused max+exp from regs,
    // 12 short4 writes. Word-stride 4*sub -> 2-way bank aliasing only (free).
    {
        const int r = t >> 4, sub = t & 15;
        float4 v[12];
        #pragma unroll
        for (int jj = 0; jj < 12; ++jj)
            v[jj] = *(const float4*)&sc[r][sub * 4 + 64 * jj];
        float mx = -1e30f;
        #pragma unroll
        for (int jj = 0; jj < 12; ++jj)
            mx = fmaxf(mx, fmaxf(fmaxf(v[jj].x, v[jj].y),
                                 fmaxf(v[jj].z, v[jj].w)));
        mx = fmaxf(mx, __shfl_xor(mx, 1, 64));
        mx = fmaxf(mx, __shfl_xor(mx, 2, 64));
        mx = fmaxf(mx, __shfl_xor(mx, 4, 64));
        mx = fmaxf(mx, __shfl_xor(mx, 8, 64));
        float s = 0.f;
        #pragma unroll
        for (int jj = 0; jj < 12; ++jj) {
            const float e0 = __expf(v[jj].x - mx);
            const float e1 = __expf(v[jj].y - mx);
            const float e2 = __expf(v[jj].z - mx);
            const float e3 = __expf(v[jj].w - mx);
            s += (e0 + e1) + (e2 + e3);
            short4 p;
            p.x = f2bf(e0); p.y = f2bf(e1); p.z = f2bf(e2); p.w = f2bf(e3);
            *(short4*)&al[r][sub * 4 + 64 * jj] = p;
        }
        s += __shfl_xor(s, 1, 64);
        s += __shfl_xor(s, 2, 64);
        s += __shfl_xor(s, 4, 64);
        s += __shfl_xor(s, 8, 64);
        if (sub == 0) rinv_s[r] = 1.f / s;
    }
    __syncthreads();

    // ---- Phase 2: h_agg = alpha @ v; wave w owns c-tile [16w, 16w+16)
    {
        f32x4 acc = {0.f, 0.f, 0.f, 0.f};
        const short* vrow = vT_ws + ((size_t)l * 64 + 16 * w + m) * NN;
        #pragma unroll 4
        for (int kt = 0; kt < 24; ++kt) {
            const int k0 = kt * 32;
            bf16x8 a = *(const bf16x8*)&al[m][k0 + quad * 8];
            bf16x8 b = *(const bf16x8*)(vrow + k0 + quad * 8);
            acc = __builtin_amdgcn_mfma_f32_16x16x32_bf16(a, b, acc, 0, 0, 0);
        }
        const int c = 16 * w + m;
        #pragma unroll
        for (int rg = 0; rg < 4; ++rg) {
            const int i = quad * 4 + rg;
            const int row = ((i0 + i) * 8 + l) * 64 + c;
            h_out[row] = h[row] + rinv_s[i] * acc[rg];
        }
    }

    // ---- Phase 3: S = alpha @ U, 4-way K-split across waves
    {
        f32x4 acc = {0.f, 0.f, 0.f, 0.f};
        const short* urow = UT_ws + ((size_t)l * 16 + m) * NN + 192 * w;
        #pragma unroll
        for (int kt = 0; kt < 6; ++kt) {
            const int k0 = kt * 32;
            bf16x8 a = *(const bf16x8*)&al[m][192 * w + k0 + quad * 8];
            bf16x8 b = *(const bf16x8*)(urow + k0 + quad * 8);
            acc = __builtin_amdgcn_mfma_f32_16x16x32_bf16(a, b, acc, 0, 0, 0);
        }
        #pragma unroll
        for (int rg = 0; rg < 4; ++rg)
            part3[w][quad * 4 + rg][m] = acc[rg];
    }
    __syncthreads();
    {
        const int i = t >> 4, u = t & 15;
        smS[i][u] = (part3[0][i][u] + part3[1][i][u] +
                     part3[2][i][u] + part3[3][i][u]) * rinv_s[i];
    }
    __syncthreads();
    if (t < 192) {
        const int i4 = t / 12, kt = t % 12, k4 = kt / 3, s4 = kt % 3;
        const int idx = ((i0 + i4) * 8 + l) * 12 + kt;
        const float cd = coord[idx];
        x_out[idx] = cd + cd * smS[i4][k4 * 4] - smS[i4][k4 * 4 + 1 + s4];
    }
}

extern "C" void kernel_launch(void* const* d_in, const int* in_sizes, int n_in,
                              void* d_out, int out_size, void* d_ws, size_t ws_size,
                              hipStream_t stream) {
    const float* h     = (const float*)d_in[0];
    const float* coord = (const float*)d_in[1];

    float* h_out = (float*)d_out;
    float* x_out = h_out + NN * LL * HH;     // 393216 floats

    short* q_ws  = (short*)d_ws;             // [L][N][64] bf16
    short* k_ws  = q_ws + NN * LL * HH;      // [L][N][64] bf16
    short* vT_ws = k_ws + NN * LL * HH;      // [L][64][N] bf16
    short* UT_ws = vT_ws + NN * LL * HH;     // [L][16][N] bf16

    qkv_kernel<<<1152, 256, 0, stream>>>(
        h, coord,
        (const float*)d_in[2],  (const float*)d_in[3],
        (const float*)d_in[4],  (const float*)d_in[5],
        (const float*)d_in[6],  (const float*)d_in[7],
        (const float*)d_in[8],  (const float*)d_in[9],
        (const float*)d_in[10], (const float*)d_in[11],
        (const float*)d_in[12], (const float*)d_in[13],
        (const float*)d_in[14], (const float*)d_in[15],
        (const float*)d_in[16],
        q_ws, k_ws, vT_ws, UT_ws);

    attn_kernel<<<(NN / IT) * LL, 256, 0, stream>>>(
        q_ws, k_ws, vT_ws, UT_ws, h, coord, h_out, x_out);
}